// Round 3
// baseline (305.868 us; speedup 1.0000x reference)
//
#include <hip/hip_runtime.h>

typedef _Float16 half8 __attribute__((ext_vector_type(8)));
typedef _Float16 half4v __attribute__((ext_vector_type(4)));
typedef float f32x4 __attribute__((ext_vector_type(4)));

// async global->LDS, 16 B per lane; LDS dest is wave-uniform base + lane*16
#define GLD16(gptr, lptr) \
    __builtin_amdgcn_global_load_lds((const __attribute__((address_space(1))) void*)(gptr), \
                                     (__attribute__((address_space(3))) void*)(lptr), 16, 0, 0)

// s_waitcnt immediates: vmcnt [3:0]|[15:14], expcnt [6:4], lgkmcnt [11:8]
#define WAIT_VM3   0x0F73  // vmcnt(3)
#define WAIT_VM0   0x0F70  // vmcnt(0)
#define WAIT_LGKM0 0xC07F  // lgkmcnt(0)

// ---------------------------------------------------------------------------
// GEMM descriptor (two independent GEMMs share one launch via blockIdx.z).
// zz = bz / SK; s = bz % SK; h = ahx ? blockIdx.x : zz & hmask;
// g = ahx ? zz : zz >> hshift.
// A += h*sAh + g*sAg; B += h*sBh + g*sBg; Coff = s*sSplit + h*sCh + g*sCg.
// In ahx mode, B-rows and C-cols get h implicitly through n0 (sBh=sCh=0).
// ---------------------------------------------------------------------------
struct GD {
    const _Float16* A; const _Float16* B; void* C;
    const float* colScale;
    long sAh, sAg, sBh, sBg, sSplit, sCh, sCg;
    int lda, ldb, ldc, K, SK, hmask, hshift;
    int ahx, outHalf, csMode, nx, ny;     // csMode: 0 none, 1 always, 2 g==0
    float alpha;
};

// ---------------------------------------------------------------------------
// hgemm3: 256x128 tile, BK=32, 512 threads (8 waves of 64x64, 4M x 2N),
// 3-slot LDS ring (3 x 24 KB = 72 KB -> 2 blocks/CU = 16 waves/CU), depth-2
// prefetch, ONE barrier per K-step, counted vmcnt.
//
// Occupancy is the round-3 change: every prior variant ran 8 waves/CU
// (2 waves/SIMD) and pinned at ~13% MfmaUtil regardless of schedule; per-step
// DS-queue drain and barrier convergence had no co-resident waves to hide
// under. 72 KB LDS + __launch_bounds__(512,4) gives 2 blocks/CU (4 waves/
// SIMD); VGPR=88 <= 128 keeps that legal.
//
// Staging: LDS tiles row-major [row][32 halves] (64 B/row); each GLD16 covers
// 16 rows x 64 B, 4 lanes per aligned line (fully coalesced). Bank-conflict
// fix (both-sides-or-neither): LDS 16-B slot s of row r holds global chunk
// c = s ^ ((r>>1)&3); staging pre-swizzles the GLOBAL source, frag reads use
// slot = kq ^ ((lm>>1)&3) -> 2-way bank aliasing only (free per m136).
//
// Ring safety: at iter t we stage into slot (t+2)%3 == (t-1)%3, whose readers
// issued their ds_reads at iter t-1 and retired them (lgkmcnt(0)) before the
// barrier that opened iter t -> no WAR hazard, for all waves.
// vmcnt(3): in-flight = stages t+1,t+2 (3 loads each); waiting to 3 drains
// stage(t+1), issued one full iteration earlier -> near-zero stall.
// K/SK must be a multiple of 32; M mult of 256, N mult of 128.
// ---------------------------------------------------------------------------
__global__ __launch_bounds__(512, 4)
void hgemm3(GD d0, GD d1, int zSplit)
{
    const bool second = (int)blockIdx.z >= zSplit;
    const GD& d = second ? d1 : d0;
    const int bz = second ? (int)blockIdx.z - zSplit : (int)blockIdx.z;
    if ((int)blockIdx.x >= d.nx || (int)blockIdx.y >= d.ny) return;

    __shared__ uint4 smem[4608];          // 72 KB: 3 ring slots x 24 KB
    char* sb = (char*)smem;
    const int tid = threadIdx.x;
    const int w = tid >> 6, l = tid & 63;
    const int m0 = blockIdx.y << 8, n0 = blockIdx.x << 7;
    const int wm = (w >> 1) << 6, wn = (w & 1) << 6;
    const int kq = l >> 4, lm = l & 15;

    const int zz = bz / d.SK, s = bz - zz * d.SK;
    const int h = d.ahx ? (int)blockIdx.x : (zz & d.hmask);
    const int g = d.ahx ? zz : (zz >> d.hshift);
    const _Float16* A = d.A + (long)h * d.sAh + (long)g * d.sAg;
    const _Float16* B = d.B + (long)h * d.sBh + (long)g * d.sBg;
    const long Coff = (long)s * d.sSplit + (long)h * d.sCh + (long)g * d.sCg;
    const int kper = d.K / d.SK, kbeg = s * kper;
    const int NT = kper >> 5;

    // staging: each instr = 16 rows x 64 B, 4 lanes per full line.
    // lane l -> row rS = w*16 + (l>>2), LDS slot l&3, global chunk cS.
    const int rS = (w << 4) + (l >> 2);
    const int cS = (l & 3) ^ ((l >> 3) & 3);      // slot ^ ((rS>>1)&3)
    const _Float16* gA0 = A + (long)(m0 + rS) * d.lda + kbeg + cS * 8;
    const _Float16* gB0 = B + (long)(n0 + rS) * d.ldb + kbeg + cS * 8;
    const int lo = w * 1024 + l * 16;

    auto stage = [&](int t) {
        char* dst = sb + (t % 3) * 24576;
        GLD16(gA0 + t * 32,                     dst + lo);           // A rows 0-127
        GLD16(gA0 + (long)128 * d.lda + t * 32, dst + 8192 + lo);    // A rows 128-255
        GLD16(gB0 + t * 32,                     dst + 16384 + lo);   // B rows 0-127
    };

    f32x4 acc[4][4] = {};
    stage(0);
    if (NT > 1) stage(1);
    if (NT > 1) __builtin_amdgcn_s_waitcnt(WAIT_VM3);
    else        __builtin_amdgcn_s_waitcnt(WAIT_VM0);
    __builtin_amdgcn_s_barrier();

    const int sw16 = ((kq ^ ((lm >> 1) & 3)) << 4);   // swizzled 16-B slot
    for (int t = 0; t < NT; ++t) {
        const char* cb = sb + (t % 3) * 24576;
        half8 af[4], bfr[4];
        const char* pa = cb + (wm + lm) * 64 + sw16;
        const char* pb = cb + 16384 + (wn + lm) * 64 + sw16;
        #pragma unroll
        for (int i = 0; i < 4; ++i) {
            af[i]  = *(const half8*)(pa + i * 1024);
            bfr[i] = *(const half8*)(pb + i * 1024);
        }
        #pragma unroll
        for (int mi = 0; mi < 4; ++mi)
            #pragma unroll
            for (int ni = 0; ni < 4; ++ni)
                acc[mi][ni] = __builtin_amdgcn_mfma_f32_16x16x32_f16(af[mi], bfr[ni], acc[mi][ni], 0, 0, 0);
        __builtin_amdgcn_s_waitcnt(WAIT_LGKM0);       // our ds_reads retired
        if (t + 2 < NT) { stage(t + 2); __builtin_amdgcn_s_waitcnt(WAIT_VM3); }
        else if (t + 1 < NT) __builtin_amdgcn_s_waitcnt(WAIT_VM0);
        __builtin_amdgcn_s_barrier();                 // tile t+1 landed+visible
    }

    // C/D layout: col = lane&15, row = (lane>>4)*4 + reg
    const int rbase = m0 + wm + kq * 4;
    #pragma unroll
    for (int mi = 0; mi < 4; ++mi) {
        #pragma unroll
        for (int ni = 0; ni < 4; ++ni) {
            const int col = n0 + wn + ni * 16 + lm;
            float cs = d.alpha;
            if (d.csMode == 1 || (d.csMode == 2 && g == 0)) cs *= d.colScale[col];
            #pragma unroll
            for (int r = 0; r < 4; ++r) {
                const long row = rbase + mi * 16 + r;
                const float v = acc[mi][ni][r] * cs;
                const long off = Coff + row * d.ldc + col;
                if (d.outHalf) ((_Float16*)d.C)[off] = (_Float16)v;
                else           ((float*)d.C)[off] = v;
            }
        }
    }
}

static GD mkgd(const _Float16* A, const _Float16* B, void* C, const float* cscale,
               long sAh, long sAg, long sBh, long sBg, long sSplit, long sCh, long sCg,
               int lda, int ldb, int ldc, int K, int SK, int hmask, int hshift,
               int ahx, int outHalf, int csMode, int nx, int ny, float alpha)
{
    GD d; d.A=A; d.B=B; d.C=C; d.colScale=cscale;
    d.sAh=sAh; d.sAg=sAg; d.sBh=sBh; d.sBg=sBg; d.sSplit=sSplit; d.sCh=sCh; d.sCg=sCg;
    d.lda=lda; d.ldb=ldb; d.ldc=ldc; d.K=K; d.SK=SK; d.hmask=hmask; d.hshift=hshift;
    d.ahx=ahx; d.outHalf=outHalf; d.csMode=csMode; d.nx=nx; d.ny=ny; d.alpha=alpha;
    return d;
}

// ---------------------------------------------------------------------------
// fp32 -> fp16 cast, z picks (x_cls | x_reg) -> d[z]
// ---------------------------------------------------------------------------
__global__ __launch_bounds__(256)
void cast_f2h(const float* __restrict__ s0, const float* __restrict__ s1,
              _Float16* __restrict__ d, int n4)
{
    const int i = blockIdx.x * 256 + threadIdx.x;
    const float* s = blockIdx.y ? s1 : s0;
    const float4 v = ((const float4*)s)[i];
    half4v o;
    o.x = (_Float16)v.x; o.y = (_Float16)v.y; o.z = (_Float16)v.z; o.w = (_Float16)v.w;
    ((half4v*)(d + (size_t)blockIdx.y * n4 * 4))[i] = o;
}

// ---------------------------------------------------------------------------
// All six weight transposes in one launch. Grid (64,64,6); idle blocks exit.
// ---------------------------------------------------------------------------
__global__ __launch_bounds__(256)
void prep_transpose(const float* __restrict__ Wq_c, const float* __restrict__ Wq_r,
                    const float* __restrict__ Wkv_c, const float* __restrict__ Wkv_r,
                    const float* __restrict__ Wl_c, const float* __restrict__ Wl_r,
                    _Float16* __restrict__ WqT, _Float16* __restrict__ WkvT,
                    _Float16* __restrict__ WlinT)
{
    __shared__ float t[32][33];
    const int z = blockIdx.z;
    const float* src; _Float16* dst; int ldsrc, lddst, nx, ky;
    switch (z) {
        case 0: src=Wq_c;  dst=WqT;            ldsrc=1024; lddst=1024; nx=32; ky=32; break;
        case 1: src=Wq_r;  dst=WqT+1048576;    ldsrc=1024; lddst=1024; nx=32; ky=32; break;
        case 2: src=Wkv_c; dst=WkvT;           ldsrc=2048; lddst=1024; nx=64; ky=32; break;
        case 3: src=Wkv_r; dst=WkvT+2097152;   ldsrc=2048; lddst=1024; nx=64; ky=32; break;
        case 4: src=Wl_c;  dst=WlinT;          ldsrc=2048; lddst=2048; nx=64; ky=64; break;
        default:src=Wl_r;  dst=WlinT+4194304;  ldsrc=2048; lddst=2048; nx=64; ky=64; break;
    }
    if ((int)blockIdx.x >= nx || (int)blockIdx.y >= ky) return;
    const int n0 = blockIdx.x << 5, k0 = blockIdx.y << 5;
    const int tx = threadIdx.x & 31, ty = threadIdx.x >> 5;
    #pragma unroll
    for (int j = ty; j < 32; j += 8)
        t[j][tx] = src[(size_t)(k0 + j) * ldsrc + n0 + tx];
    __syncthreads();
    #pragma unroll
    for (int j = ty; j < 32; j += 8)
        dst[(size_t)(n0 + j) * lddst + k0 + tx] = (_Float16)t[tx][j];
}

// ---------------------------------------------------------------------------
// Phase-3 fused kernel: by blockIdx.x range —
//  [0,2048):        q-norm from direct qh [2][512][1024]
//  [2048,18432):    kv-norm from direct kvh [2][2048][2048] + x_ori emission
//  [18432,22528):   V^T: vT[g][n][k] = kvh[g][k][1024+n]
// ---------------------------------------------------------------------------
__global__ __launch_bounds__(256)
void phase3(const _Float16* __restrict__ qh, const _Float16* __restrict__ kvh,
            _Float16* __restrict__ qn, _Float16* __restrict__ kn,
            _Float16* __restrict__ vn, _Float16* __restrict__ x_ori,
            _Float16* __restrict__ vT)
{
    __shared__ float t[32][33];
    const int b = blockIdx.x;
    if (b < 2048) {
        const int vid = b * 4 + (threadIdx.x >> 6);
        const int lane = threadIdx.x & 63;
        const int g = vid >> 12, rr = vid & 4095, row = rr >> 3, hh = rr & 7;
        const size_t o = (size_t)g * 524288 + (size_t)row * 1024 + hh * 128 + lane * 2;
        const float a = (float)qh[o], bb = (float)qh[o + 1];
        float ss = a * a + bb * bb;
        #pragma unroll
        for (int d = 32; d > 0; d >>= 1) ss += __shfl_xor(ss, d, 64);
        const float inv = rsqrtf(ss);
        qn[o] = (_Float16)(a * inv); qn[o + 1] = (_Float16)(bb * inv);
    } else if (b < 18432) {
        const int vid = (b - 2048) * 4 + (threadIdx.x >> 6);   // [0, 65536)
        const int lane = threadIdx.x & 63;
        const int half_ = vid >> 15;            // 0 = K, 1 = V
        const int r15 = vid & 32767;
        const int g = r15 >> 14, rr = r15 & 16383, row = rr >> 3, hh = rr & 7;
        const size_t so = (size_t)g * 4194304 + (size_t)row * 2048
                        + half_ * 1024 + hh * 128 + lane * 2;
        const float a = (float)kvh[so], bb = (float)kvh[so + 1];
        float ss = a * a + bb * bb;
        #pragma unroll
        for (int d = 32; d > 0; d >>= 1) ss += __shfl_xor(ss, d, 64);
        const float inv = rsqrtf(ss);
        const size_t dofs = (size_t)g * 2097152 + (size_t)row * 1024 + hh * 128 + lane * 2;
        _Float16* dp = (half_ ? vn : kn) + dofs;
        dp[0] = (_Float16)(a * inv); dp[1] = (_Float16)(bb * inv);
        if (half_ == 1 && row < 512) {
            _Float16* xo = x_ori + (size_t)g * 524288 + (size_t)row * 1024 + hh * 128 + lane * 2;
            xo[0] = (_Float16)a; xo[1] = (_Float16)bb;
        }
    } else {
        const int vb = b - 18432;               // [0, 4096)
        const int g = vb >> 11, r = vb & 2047;
        const int n0 = (r & 31) << 5, k0 = (r >> 5) << 5;
        const int tx = threadIdx.x & 31, ty = threadIdx.x >> 5;
        const _Float16* s0 = kvh + (size_t)g * 4194304 + 1024;
        #pragma unroll
        for (int j = ty; j < 32; j += 8)
            t[j][tx] = (float)s0[(size_t)(k0 + j) * 2048 + n0 + tx];
        __syncthreads();
        _Float16* d = vT + (size_t)g * 2097152;
        #pragma unroll
        for (int j = ty; j < 32; j += 8)
            d[(size_t)(n0 + j) * 2048 + k0 + tx] = (_Float16)t[tx][j];
    }
}

// ---------------------------------------------------------------------------
// Block reduce (256 threads, 4 waves). OP: 0 sum, 1 max
// ---------------------------------------------------------------------------
template<int OP>
__device__ __forceinline__ float bred(float v, float* lds)
{
    #pragma unroll
    for (int o = 32; o > 0; o >>= 1) {
        const float u = __shfl_xor(v, o, 64);
        v = OP ? fmaxf(v, u) : v + u;
    }
    __syncthreads();
    if ((threadIdx.x & 63) == 0) lds[threadIdx.x >> 6] = v;
    __syncthreads();
    return OP ? fmaxf(fmaxf(lds[0], lds[1]), fmaxf(lds[2], lds[3]))
              : lds[0] + lds[1] + lds[2] + lds[3];
}

// ---------------------------------------------------------------------------
// Fused: per q row — dual softmax per head + blend -> fp16 attn + head-mean,
// then round-2 masked renorm weights.
// S16 [16][512][2048] fp16 (0-7 cls, 8-15 reg); simPart [2][512][2048] f32.
// ---------------------------------------------------------------------------
__global__ __launch_bounds__(256)
void sb2_kernel(const _Float16* __restrict__ S16, const float* __restrict__ simPart,
                _Float16* __restrict__ attn,
                _Float16* __restrict__ wc, _Float16* __restrict__ wr)
{
    __shared__ float lds[4];
    const int q = blockIdx.x, t = threadIdx.x;
    float asum[8] = {};
    for (int hh = 0; hh < 8; ++hh) {
        const size_t rb = (size_t)(hh * 512 + q) * 2048;
        float vc[8], vr[8];
        float mc = -1e30f, mr = -1e30f;
        #pragma unroll
        for (int j = 0; j < 8; ++j) {
            vc[j] = (float)S16[rb + t + 256 * j];
            vr[j] = (float)S16[8388608 + rb + t + 256 * j];
            mc = fmaxf(mc, vc[j]); mr = fmaxf(mr, vr[j]);
        }
        mc = bred<1>(mc, lds);
        mr = bred<1>(mr, lds);
        float sc = 0.f, sr = 0.f;
        #pragma unroll
        for (int j = 0; j < 8; ++j) {
            vc[j] = expf(vc[j] - mc); sc += vc[j];
            vr[j] = expf(vr[j] - mr); sr += vr[j];
        }
        sc = bred<0>(sc, lds);
        sr = bred<0>(sr, lds);
        const float ic = 0.5f / sc, ir = 0.5f / sr;
        #pragma unroll
        for (int j = 0; j < 8; ++j) {
            const float a = vc[j] * ic + vr[j] * ir;
            attn[rb + t + 256 * j] = (_Float16)a;
            asum[j] += a;
        }
    }
    float mx = -1e30f;
    #pragma unroll
    for (int j = 0; j < 8; ++j) { asum[j] *= 0.125f; mx = fmaxf(mx, asum[j]); }
    mx = bred<1>(mx, lds);
    float em[8], emo[8];
    float s1 = 0.f, s2 = 0.f;
    const size_t qb = (size_t)q * 2048;
    #pragma unroll
    for (int j = 0; j < 8; ++j) {
        const size_t o = qb + t + 256 * j;
        const float sim = simPart[o];
        const float reg = simPart[1048576 + o];
        const float e = expf(asum[j] - mx);
        const float m  = sim > 0.75f ? 1.f : 0.f;
        const float mo = reg > 0.99f ? 1.f : 0.f;
        em[j] = e * m; emo[j] = e * m * mo;
        s1 += em[j]; s2 += emo[j];
    }
    s1 = bred<0>(s1, lds);
    s2 = bred<0>(s2, lds);
    const float i1 = 1.f / s1, i2 = 1.f / s2;
    #pragma unroll
    for (int j = 0; j < 8; ++j) {
        wc[qb + t + 256 * j] = (_Float16)(em[j] * i1);
        wr[qb + t + 256 * j] = (_Float16)(emo[j] * i2);
    }
}

// ---------------------------------------------------------------------------
// xcat16 [2][512][2048]: cols<1024 = 4-way reduce of attn@V partials,
// cols>=1024 = x_ori.
// ---------------------------------------------------------------------------
__global__ __launch_bounds__(256)
void build_xcat(const float* __restrict__ xcatPart, const _Float16* __restrict__ x_ori,
                _Float16* __restrict__ xcat)
{
    const int idx = blockIdx.x * 256 + threadIdx.x;   // 2*512*2048
    const int j = idx & 2047;
    const int n = (idx >> 11) & 511;
    const int g = idx >> 20;
    _Float16 v;
    if (j < 1024) {
        float a = 0.f;
        #pragma unroll
        for (int s = 0; s < 4; ++s)
            a += xcatPart[(size_t)s * 1048576 + (size_t)g * 524288 + n * 1024 + j];
        v = (_Float16)a;
    } else {
        v = x_ori[(size_t)g * 524288 + (size_t)n * 1024 + (j - 1024)];
    }
    xcat[idx] = v;
}

// ---------------------------------------------------------------------------
// finalize d_out [2][512][3072]: cols<1024 4-way avePart reduce; cols>=1024
// 4-way outPart reduce + bias.
// ---------------------------------------------------------------------------
__global__ __launch_bounds__(256)
void finalize(const float* __restrict__ avePart, const float* __restrict__ outPart,
              const float* __restrict__ b_lin, const float* __restrict__ b_lin_reg,
              float* __restrict__ out)
{
    const int idx = blockIdx.x * 256 + threadIdx.x;   // 2*512*3072
    const int c = idx % 3072;
    const int r = (idx / 3072) & 511;
    const int g = idx / (3072 * 512);
    float v;
    if (c < 1024) {
        v = 0.f;
        #pragma unroll
        for (int s = 0; s < 4; ++s)
            v += avePart[(size_t)s * 1048576 + (size_t)g * 524288 + r * 1024 + c];
    } else {
        const int cc = c - 1024;
        v = (g ? b_lin_reg : b_lin)[cc];
        #pragma unroll
        for (int s = 0; s < 4; ++s)
            v += outPart[(size_t)s * 2097152 + (size_t)g * 1048576 + r * 2048 + cc];
    }
    out[idx] = v;
}

extern "C" void kernel_launch(void* const* d_in, const int* in_sizes, int n_in,
                              void* d_out, int out_size, void* d_ws, size_t ws_size,
                              hipStream_t stream)
{
    const float* x_cls     = (const float*)d_in[0];
    const float* x_reg     = (const float*)d_in[1];
    const float* cls_score = (const float*)d_in[2];
    const float* W_q_cls   = (const float*)d_in[4];
    const float* W_kv_cls  = (const float*)d_in[5];
    const float* W_q_reg   = (const float*)d_in[6];
    const float* W_kv_reg  = (const float*)d_in[7];
    const float* W_lin     = (const float*)d_in[8];
    const float* b_lin     = (const float*)d_in[9];
    const float* W_lin_reg = (const float*)d_in[10];
    const float* b_lin_reg = (const float*)d_in[11];
    float* out = (float*)d_out;

    if (ws_size < (size_t)124 * 1048576) return;

    // Workspace overlay (MiB offsets), peak 124 MiB:
    char* W = (char*)d_ws;
    auto at = [&](size_t mb) { return (void*)(W + mb * 1048576); };
    _Float16* WlinT   = (_Float16*)at(0);    // prep -> M8                 [0,16)
    _Float16* vT      = (_Float16*)at(16);   // phase3 -> M3               [16,24)
    _Float16* x_ori   = (_Float16*)at(24);   // phase3 -> build_xcat       [24,26)
    _Float16* w_c     = (_Float16*)at(26);   // sb2 -> M3                  [26,28)
    _Float16* w_r     = (_Float16*)at(28);   //                            [28,30)
    _Float16* qn      = (_Float16*)at(30);   // phase3 -> M2               [30,32)
    _Float16* kvh     = (_Float16*)at(32);   // M1 (direct) -> phase3      [32,48)
    float*    simPart = (float*)at(32);      // M2 -> sb2 (kvh dead)       [32,40)
    float*    outPart = (float*)at(32);      // M8 -> finalize (sim dead)  [32,64)
    _Float16* qh      = (_Float16*)at(64);   // M1 -> phase3               [64,66)
    _Float16* WqT     = (_Float16*)at(66);   // prep -> M1                 [66,70)
    _Float16* WkvT    = (_Float16*)at(70);   // prep -> M1                 [70,78)
    _Float16* kn      = (_Float16*)at(66);   // phase3 -> M2 (WqT dead)    [66,74)
    _Float16* vn      = (_Float16*)at(74);   // phase3 -> M2               [74,82)
    _Float16* attn_h  = (_Float16*)at(66);   // sb2 -> M3 (kn/vn dead)     [66,82)
    _Float16* xbf     = (_Float16*)at(82);   // cast -> M1                 [82,90)
    _Float16* xcat16  = (_Float16*)at(82);   // build_xcat -> M8 (xbf dead)[82,86)
    _Float16* S16     = (_Float16*)at(90);   // M2 -> sb2                  [90,122)
    float*    xcatPart= (float*)at(90);      // M3 -> build_xcat (S16 dead)[90,106)
    float*    avePart = (float*)at(106);     // M3 -> finalize             [106,122)

    // Phase 1: prep
    cast_f2h<<<dim3(2048, 2), 256, 0, stream>>>(x_cls, x_reg, xbf, 524288);
    prep_transpose<<<dim3(64, 64, 6), 256, 0, stream>>>(
        W_q_cls, W_q_reg, W_kv_cls, W_kv_reg, W_lin, W_lin_reg, WqT, WkvT, WlinT);

    // Phase 2 (M1): q-proj (SK=1, fp16) + kv-proj (SK=1, fp16 direct).
    // 288 active blocks <= 512 resident at 2 blocks/CU -> single cohort.
    {
        GD q  = mkgd(xbf, WqT, qh, nullptr,
                     0, 2097152, 0, 1048576, 0, 0, 524288,
                     1024, 1024, 1024, 1024, 1, 0, 0, 0, 1, 0, 8, 2, 1.f);
        GD kv = mkgd(xbf, WkvT, kvh, nullptr,
                     0, 2097152, 0, 2097152, 0, 0, 4194304,
                     1024, 1024, 2048, 1024, 1, 0, 0, 0, 1, 0, 16, 8, 1.f);
        hgemm3<<<dim3(16, 8, 4), 512, 0, stream>>>(q, kv, 2);
    }

    // Phase 3: fused norms + V^T (direct kvh, no partial reduce)
    phase3<<<22528, 256, 0, stream>>>(qh, kvh, qn, kn, vn, x_ori, vT);

    // Phase 4 (M2): v-sim (SK=1, fp32 direct) + scores (z=16, fp16)
    {
        GD vs = mkgd(vn, vn, simPart, nullptr,
                     0, 2097152, 0, 2097152, 0, 0, 1048576,
                     1024, 1024, 2048, 1024, 1, 0, 0, 0, 0, 0, 16, 2, 0.125f);
        GD sc = mkgd(qn, kn, S16, cls_score,
                     128, 524288, 128, 2097152, 0, 1048576, 8388608,
                     1024, 1024, 2048, 128, 1, 7, 3, 0, 1, 2, 16, 2, 25.f);
        hgemm3<<<dim3(16, 2, 18), 512, 0, stream>>>(vs, sc, 2);
    }

    // Phase 5: fused dual softmax + blend + head-mean + round2 weights
    sb2_kernel<<<512, 256, 0, stream>>>(S16, simPart, attn_h, w_c, w_r);

    // Phase 6 (M3): attn@V (AHX, SK=4) + ave (SK=4), both fp32 partials
    {
        GD av = mkgd(attn_h, vT, xcatPart, nullptr,
                     1048576, 0, 0, 2097152, 1048576, 0, 524288,
                     2048, 2048, 1024, 2048, 4, 0, 0, 1, 0, 0, 8, 2, 1.f);
        GD ae = mkgd(w_c, vT, avePart, nullptr,
                     0, 1048576, 0, 2097152, 1048576, 0, 524288,
                     2048, 2048, 1024, 2048, 4, 0, 0, 0, 0, 0, 8, 2, 1.f);
        hgemm3<<<dim3(8, 2, 16), 512, 0, stream>>>(av, ae, 8);
    }

    // Phase 7: xcat assembly (4-way reduce + x_ori)
    build_xcat<<<8192, 256, 0, stream>>>(xcatPart, x_ori, xcat16);

    // Phase 8 (M8): out-linears (SK=4, fp32 partials)
    {
        GD ol = mkgd(xcat16, WlinT, outPart, nullptr,
                     0, 1048576, 0, 4194304, 2097152, 0, 1048576,
                     2048, 2048, 2048, 2048, 4, 0, 0, 0, 0, 0, 16, 2, 1.f);
        hgemm3<<<dim3(16, 2, 8), 512, 0, stream>>>(ol, ol, 8);
    }

    // Phase 9: write d_out
    finalize<<<12288, 256, 0, stream>>>(avePart, outPart, b_lin, b_lin_reg, out);
}

// Round 4
// 296.018 us; speedup vs baseline: 1.0333x; 1.0333x over previous
//
#include <hip/hip_runtime.h>

typedef _Float16 half8 __attribute__((ext_vector_type(8)));
typedef _Float16 half4v __attribute__((ext_vector_type(4)));
typedef float f32x4 __attribute__((ext_vector_type(4)));

// async global->LDS, 16 B per lane; LDS dest is wave-uniform base + lane*16
#define GLD16(gptr, lptr) \
    __builtin_amdgcn_global_load_lds((const __attribute__((address_space(1))) void*)(gptr), \
                                     (__attribute__((address_space(3))) void*)(lptr), 16, 0, 0)

// s_waitcnt immediates: vmcnt [3:0]|[15:14], expcnt [6:4], lgkmcnt [11:8]
#define WAIT_VM3   0x0F73  // vmcnt(3)
#define WAIT_VM0   0x0F70  // vmcnt(0)
#define WAIT_LGKM0 0xC07F  // lgkmcnt(0)

// ---------------------------------------------------------------------------
// GEMM descriptor (two independent GEMMs share one launch via blockIdx.z).
// zz = bz / SK; s = bz % SK; h = ahx ? blockIdx.x : zz & hmask;
// g = ahx ? zz : zz >> hshift.
// A += h*sAh + g*sAg; B += h*sBh + g*sBg; Coff = s*sSplit + h*sCh + g*sCg.
// In ahx mode, B-rows and C-cols get h implicitly through n0 (sBh=sCh=0).
// normMode (fused epilogues; problem-constant strides):
//   0: plain C store (alpha/colScale path)
//   1: q-norm   -> C=qn [2][512][1024], row-L2-normalized over block's 128 cols
//   2: kv-norm  -> cols<1024: C=kn [2][2048][1024] normalized;
//                  cols>=1024: vnp=vn normalized, vtp=vT raw transposed,
//                  xop=x_ori raw (rows<512)
// ---------------------------------------------------------------------------
struct GD {
    const _Float16* A; const _Float16* B; void* C;
    const float* colScale;
    _Float16 *vnp, *vtp, *xop;
    long sAh, sAg, sBh, sBg, sSplit, sCh, sCg;
    int lda, ldb, ldc, K, SK, hmask, hshift;
    int ahx, outHalf, csMode, nx, ny, normMode;   // csMode: 0 none, 1 always, 2 g==0
    float alpha;
};

// ---------------------------------------------------------------------------
// hgemm3: 256x128 tile, BK=32, 512 threads (8 waves of 64x64, 4M x 2N),
// 3-slot LDS ring (72 KB -> 2 blocks/CU), depth-2 prefetch, ONE barrier per
// K-step, counted vmcnt.
// Staging: LDS tiles row-major [row][32 halves]; each GLD16 covers 16 rows x
// 64 B, 4 lanes per aligned line (fully coalesced). Bank-conflict fix
// (both-sides-or-neither): LDS 16-B slot s of row r holds global chunk
// c = s ^ ((r>>1)&3); staging pre-swizzles the GLOBAL source, frag reads use
// slot = kq ^ ((lm>>1)&3)  (SQ_LDS_BANK_CONFLICT == 0 measured).
// Ring safety: stage target slot's readers retired (lgkmcnt(0)) one barrier
// earlier. vmcnt(3) waits only for loads issued a full iteration ago.
// K/SK mult of 32; M mult of 256, N mult of 128.
// ---------------------------------------------------------------------------
__global__ __launch_bounds__(512, 4)
void hgemm3(GD d0, GD d1, int zSplit)
{
    const bool second = (int)blockIdx.z >= zSplit;
    const GD& d = second ? d1 : d0;
    const int bz = second ? (int)blockIdx.z - zSplit : (int)blockIdx.z;
    if ((int)blockIdx.x >= d.nx || (int)blockIdx.y >= d.ny) return;

    __shared__ uint4 smem[4608];          // 72 KB: 3 ring slots x 24 KB
    char* sb = (char*)smem;
    const int tid = threadIdx.x;
    const int w = tid >> 6, l = tid & 63;
    const int m0 = blockIdx.y << 8, n0 = blockIdx.x << 7;
    const int wm = (w >> 1) << 6, wn = (w & 1) << 6;
    const int kq = l >> 4, lm = l & 15;

    const int zz = bz / d.SK, s = bz - zz * d.SK;
    const int h = d.ahx ? (int)blockIdx.x : (zz & d.hmask);
    const int g = d.ahx ? zz : (zz >> d.hshift);
    const _Float16* A = d.A + (long)h * d.sAh + (long)g * d.sAg;
    const _Float16* B = d.B + (long)h * d.sBh + (long)g * d.sBg;
    const long Coff = (long)s * d.sSplit + (long)h * d.sCh + (long)g * d.sCg;
    const int kper = d.K / d.SK, kbeg = s * kper;
    const int NT = kper >> 5;

    // staging: each instr = 16 rows x 64 B, 4 lanes per full line.
    const int rS = (w << 4) + (l >> 2);
    const int cS = (l & 3) ^ ((l >> 3) & 3);      // slot ^ ((rS>>1)&3)
    const _Float16* gA0 = A + (long)(m0 + rS) * d.lda + kbeg + cS * 8;
    const _Float16* gB0 = B + (long)(n0 + rS) * d.ldb + kbeg + cS * 8;
    const int lo = w * 1024 + l * 16;

    auto stage = [&](int t) {
        char* dst = sb + (t % 3) * 24576;
        GLD16(gA0 + t * 32,                     dst + lo);           // A rows 0-127
        GLD16(gA0 + (long)128 * d.lda + t * 32, dst + 8192 + lo);    // A rows 128-255
        GLD16(gB0 + t * 32,                     dst + 16384 + lo);   // B rows 0-127
    };

    f32x4 acc[4][4] = {};
    stage(0);
    if (NT > 1) stage(1);
    if (NT > 1) __builtin_amdgcn_s_waitcnt(WAIT_VM3);
    else        __builtin_amdgcn_s_waitcnt(WAIT_VM0);
    __builtin_amdgcn_s_barrier();

    const int sw16 = ((kq ^ ((lm >> 1) & 3)) << 4);   // swizzled 16-B slot
    for (int t = 0; t < NT; ++t) {
        const char* cb = sb + (t % 3) * 24576;
        half8 af[4], bfr[4];
        const char* pa = cb + (wm + lm) * 64 + sw16;
        const char* pb = cb + 16384 + (wn + lm) * 64 + sw16;
        #pragma unroll
        for (int i = 0; i < 4; ++i) {
            af[i]  = *(const half8*)(pa + i * 1024);
            bfr[i] = *(const half8*)(pb + i * 1024);
        }
        #pragma unroll
        for (int mi = 0; mi < 4; ++mi)
            #pragma unroll
            for (int ni = 0; ni < 4; ++ni)
                acc[mi][ni] = __builtin_amdgcn_mfma_f32_16x16x32_f16(af[mi], bfr[ni], acc[mi][ni], 0, 0, 0);
        __builtin_amdgcn_s_waitcnt(WAIT_LGKM0);       // our ds_reads retired
        if (t + 2 < NT) { stage(t + 2); __builtin_amdgcn_s_waitcnt(WAIT_VM3); }
        else if (t + 1 < NT) __builtin_amdgcn_s_waitcnt(WAIT_VM0);
        __builtin_amdgcn_s_barrier();                 // tile t+1 landed+visible
    }

    // C/D layout: col = lane&15, row = (lane>>4)*4 + reg
    if (d.normMode == 0) {
        const int rbase = m0 + wm + kq * 4;
        #pragma unroll
        for (int mi = 0; mi < 4; ++mi) {
            #pragma unroll
            for (int ni = 0; ni < 4; ++ni) {
                const int col = n0 + wn + ni * 16 + lm;
                float cs = d.alpha;
                if (d.csMode == 1 || (d.csMode == 2 && g == 0)) cs *= d.colScale[col];
                #pragma unroll
                for (int r = 0; r < 4; ++r) {
                    const long row = rbase + mi * 16 + r;
                    const float v = acc[mi][ni][r] * cs;
                    const long off = Coff + row * d.ldc + col;
                    if (d.outHalf) ((_Float16*)d.C)[off] = (_Float16)v;
                    else           ((float*)d.C)[off] = v;
                }
            }
        }
        return;
    }

    // ---- fused L2-norm epilogue (block cols = exactly one 128-dim head) ----
    // Per-row sum of squares over this block's 128 cols: lane sums its 4 ni
    // values, 16-lane (lm) shfl reduce covers 64 cols; cross-wave (wn pair)
    // via 2 KB LDS. Ring is dead (all ds_reads retired before last barrier).
    float* part = (float*)sb;                 // part[2][256]
    float ssq[4][4];
    #pragma unroll
    for (int mi = 0; mi < 4; ++mi)
        #pragma unroll
        for (int r = 0; r < 4; ++r) {
            float sq = 0.f;
            #pragma unroll
            for (int ni = 0; ni < 4; ++ni) { const float v = acc[mi][ni][r]; sq += v * v; }
            sq += __shfl_xor(sq, 1, 64);
            sq += __shfl_xor(sq, 2, 64);
            sq += __shfl_xor(sq, 4, 64);
            sq += __shfl_xor(sq, 8, 64);
            ssq[mi][r] = sq;
        }
    if (lm == 0) {
        #pragma unroll
        for (int mi = 0; mi < 4; ++mi)
            #pragma unroll
            for (int r = 0; r < 4; ++r)
                part[(w & 1) * 256 + wm + kq * 4 + mi * 16 + r] = ssq[mi][r];
    }
    __syncthreads();

    #pragma unroll
    for (int mi = 0; mi < 4; ++mi) {
        #pragma unroll
        for (int r = 0; r < 4; ++r) {
            const int rl = wm + kq * 4 + mi * 16 + r;
            const float inv = rsqrtf(part[rl] + part[256 + rl]);
            const long rg = m0 + rl;
            if (d.normMode == 1) {
                #pragma unroll
                for (int ni = 0; ni < 4; ++ni) {
                    const int col = n0 + wn + ni * 16 + lm;
                    ((_Float16*)d.C)[(long)g * 524288 + rg * 1024 + col] =
                        (_Float16)(acc[mi][ni][r] * inv);
                }
            } else if (n0 < 1024) {           // K half -> kn
                #pragma unroll
                for (int ni = 0; ni < 4; ++ni) {
                    const int col = n0 + wn + ni * 16 + lm;
                    ((_Float16*)d.C)[(long)g * 2097152 + rg * 1024 + col] =
                        (_Float16)(acc[mi][ni][r] * inv);
                }
            } else {                          // V half -> vn + x_ori
                #pragma unroll
                for (int ni = 0; ni < 4; ++ni) {
                    const int nL = n0 - 1024 + wn + ni * 16 + lm;
                    d.vnp[(long)g * 2097152 + rg * 1024 + nL] =
                        (_Float16)(acc[mi][ni][r] * inv);
                    if (rg < 512)
                        d.xop[(long)g * 524288 + rg * 1024 + nL] = (_Float16)acc[mi][ni][r];
                }
            }
        }
    }
    // vT raw transposed store (V half): regs r=0..3 are consecutive rows ->
    // one aligned 8-B store per (mi,ni).
    if (d.normMode == 2 && n0 >= 1024) {
        #pragma unroll
        for (int mi = 0; mi < 4; ++mi)
            #pragma unroll
            for (int ni = 0; ni < 4; ++ni) {
                const int nL = n0 - 1024 + wn + ni * 16 + lm;
                half4v t;
                t.x = (_Float16)acc[mi][ni][0]; t.y = (_Float16)acc[mi][ni][1];
                t.z = (_Float16)acc[mi][ni][2]; t.w = (_Float16)acc[mi][ni][3];
                *(half4v*)(d.vtp + (long)g * 2097152 + (long)nL * 2048
                           + m0 + wm + kq * 4 + mi * 16) = t;
            }
    }
}

static GD mkgd(const _Float16* A, const _Float16* B, void* C, const float* cscale,
               long sAh, long sAg, long sBh, long sBg, long sSplit, long sCh, long sCg,
               int lda, int ldb, int ldc, int K, int SK, int hmask, int hshift,
               int ahx, int outHalf, int csMode, int nx, int ny, float alpha)
{
    GD d; d.A=A; d.B=B; d.C=C; d.colScale=cscale;
    d.vnp=nullptr; d.vtp=nullptr; d.xop=nullptr;
    d.sAh=sAh; d.sAg=sAg; d.sBh=sBh; d.sBg=sBg; d.sSplit=sSplit; d.sCh=sCh; d.sCg=sCg;
    d.lda=lda; d.ldb=ldb; d.ldc=ldc; d.K=K; d.SK=SK; d.hmask=hmask; d.hshift=hshift;
    d.ahx=ahx; d.outHalf=outHalf; d.csMode=csMode; d.nx=nx; d.ny=ny; d.normMode=0;
    d.alpha=alpha;
    return d;
}

// ---------------------------------------------------------------------------
// fp32 -> fp16 cast, z picks (x_cls | x_reg) -> d[z]
// ---------------------------------------------------------------------------
__global__ __launch_bounds__(256)
void cast_f2h(const float* __restrict__ s0, const float* __restrict__ s1,
              _Float16* __restrict__ d, int n4)
{
    const int i = blockIdx.x * 256 + threadIdx.x;
    const float* s = blockIdx.y ? s1 : s0;
    const float4 v = ((const float4*)s)[i];
    half4v o;
    o.x = (_Float16)v.x; o.y = (_Float16)v.y; o.z = (_Float16)v.z; o.w = (_Float16)v.w;
    ((half4v*)(d + (size_t)blockIdx.y * n4 * 4))[i] = o;
}

// ---------------------------------------------------------------------------
// All six weight transposes in one launch. Grid (64,64,6); idle blocks exit.
// ---------------------------------------------------------------------------
__global__ __launch_bounds__(256)
void prep_transpose(const float* __restrict__ Wq_c, const float* __restrict__ Wq_r,
                    const float* __restrict__ Wkv_c, const float* __restrict__ Wkv_r,
                    const float* __restrict__ Wl_c, const float* __restrict__ Wl_r,
                    _Float16* __restrict__ WqT, _Float16* __restrict__ WkvT,
                    _Float16* __restrict__ WlinT)
{
    __shared__ float t[32][33];
    const int z = blockIdx.z;
    const float* src; _Float16* dst; int ldsrc, lddst, nx, ky;
    switch (z) {
        case 0: src=Wq_c;  dst=WqT;            ldsrc=1024; lddst=1024; nx=32; ky=32; break;
        case 1: src=Wq_r;  dst=WqT+1048576;    ldsrc=1024; lddst=1024; nx=32; ky=32; break;
        case 2: src=Wkv_c; dst=WkvT;           ldsrc=2048; lddst=1024; nx=64; ky=32; break;
        case 3: src=Wkv_r; dst=WkvT+2097152;   ldsrc=2048; lddst=1024; nx=64; ky=32; break;
        case 4: src=Wl_c;  dst=WlinT;          ldsrc=2048; lddst=2048; nx=64; ky=64; break;
        default:src=Wl_r;  dst=WlinT+4194304;  ldsrc=2048; lddst=2048; nx=64; ky=64; break;
    }
    if ((int)blockIdx.x >= nx || (int)blockIdx.y >= ky) return;
    const int n0 = blockIdx.x << 5, k0 = blockIdx.y << 5;
    const int tx = threadIdx.x & 31, ty = threadIdx.x >> 5;
    #pragma unroll
    for (int j = ty; j < 32; j += 8)
        t[j][tx] = src[(size_t)(k0 + j) * ldsrc + n0 + tx];
    __syncthreads();
    #pragma unroll
    for (int j = ty; j < 32; j += 8)
        dst[(size_t)(n0 + j) * lddst + k0 + tx] = (_Float16)t[tx][j];
}

// ---------------------------------------------------------------------------
// Block reduce (256 threads, 4 waves). OP: 0 sum, 1 max
// ---------------------------------------------------------------------------
template<int OP>
__device__ __forceinline__ float bred(float v, float* lds)
{
    #pragma unroll
    for (int o = 32; o > 0; o >>= 1) {
        const float u = __shfl_xor(v, o, 64);
        v = OP ? fmaxf(v, u) : v + u;
    }
    __syncthreads();
    if ((threadIdx.x & 63) == 0) lds[threadIdx.x >> 6] = v;
    __syncthreads();
    return OP ? fmaxf(fmaxf(lds[0], lds[1]), fmaxf(lds[2], lds[3]))
              : lds[0] + lds[1] + lds[2] + lds[3];
}

// ---------------------------------------------------------------------------
// Fused: per q row — dual softmax per head + blend -> fp16 attn + head-mean,
// then round-2 masked renorm weights.
// S16 [16][512][2048] fp16 (0-7 cls, 8-15 reg); simPart [2][512][2048] f32.
// ---------------------------------------------------------------------------
__global__ __launch_bounds__(256)
void sb2_kernel(const _Float16* __restrict__ S16, const float* __restrict__ simPart,
                _Float16* __restrict__ attn,
                _Float16* __restrict__ wc, _Float16* __restrict__ wr)
{
    __shared__ float lds[4];
    const int q = blockIdx.x, t = threadIdx.x;
    float asum[8] = {};
    for (int hh = 0; hh < 8; ++hh) {
        const size_t rb = (size_t)(hh * 512 + q) * 2048;
        float vc[8], vr[8];
        float mc = -1e30f, mr = -1e30f;
        #pragma unroll
        for (int j = 0; j < 8; ++j) {
            vc[j] = (float)S16[rb + t + 256 * j];
            vr[j] = (float)S16[8388608 + rb + t + 256 * j];
            mc = fmaxf(mc, vc[j]); mr = fmaxf(mr, vr[j]);
        }
        mc = bred<1>(mc, lds);
        mr = bred<1>(mr, lds);
        float sc = 0.f, sr = 0.f;
        #pragma unroll
        for (int j = 0; j < 8; ++j) {
            vc[j] = expf(vc[j] - mc); sc += vc[j];
            vr[j] = expf(vr[j] - mr); sr += vr[j];
        }
        sc = bred<0>(sc, lds);
        sr = bred<0>(sr, lds);
        const float ic = 0.5f / sc, ir = 0.5f / sr;
        #pragma unroll
        for (int j = 0; j < 8; ++j) {
            const float a = vc[j] * ic + vr[j] * ir;
            attn[rb + t + 256 * j] = (_Float16)a;
            asum[j] += a;
        }
    }
    float mx = -1e30f;
    #pragma unroll
    for (int j = 0; j < 8; ++j) { asum[j] *= 0.125f; mx = fmaxf(mx, asum[j]); }
    mx = bred<1>(mx, lds);
    float em[8], emo[8];
    float s1 = 0.f, s2 = 0.f;
    const size_t qb = (size_t)q * 2048;
    #pragma unroll
    for (int j = 0; j < 8; ++j) {
        const size_t o = qb + t + 256 * j;
        const float sim = simPart[o];
        const float reg = simPart[1048576 + o];
        const float e = expf(asum[j] - mx);
        const float m  = sim > 0.75f ? 1.f : 0.f;
        const float mo = reg > 0.99f ? 1.f : 0.f;
        em[j] = e * m; emo[j] = e * m * mo;
        s1 += em[j]; s2 += emo[j];
    }
    s1 = bred<0>(s1, lds);
    s2 = bred<0>(s2, lds);
    const float i1 = 1.f / s1, i2 = 1.f / s2;
    #pragma unroll
    for (int j = 0; j < 8; ++j) {
        wc[qb + t + 256 * j] = (_Float16)(em[j] * i1);
        wr[qb + t + 256 * j] = (_Float16)(emo[j] * i2);
    }
}

// ---------------------------------------------------------------------------
// xcat16 [2][512][2048]: cols<1024 = 4-way reduce of attn@V partials,
// cols>=1024 = x_ori.
// ---------------------------------------------------------------------------
__global__ __launch_bounds__(256)
void build_xcat(const float* __restrict__ xcatPart, const _Float16* __restrict__ x_ori,
                _Float16* __restrict__ xcat)
{
    const int idx = blockIdx.x * 256 + threadIdx.x;   // 2*512*2048
    const int j = idx & 2047;
    const int n = (idx >> 11) & 511;
    const int g = idx >> 20;
    _Float16 v;
    if (j < 1024) {
        float a = 0.f;
        #pragma unroll
        for (int s = 0; s < 4; ++s)
            a += xcatPart[(size_t)s * 1048576 + (size_t)g * 524288 + n * 1024 + j];
        v = (_Float16)a;
    } else {
        v = x_ori[(size_t)g * 524288 + (size_t)n * 1024 + (j - 1024)];
    }
    xcat[idx] = v;
}

// ---------------------------------------------------------------------------
// finalize d_out [2][512][3072]: cols<1024 4-way avePart reduce; cols>=1024
// 4-way outPart reduce + bias.
// ---------------------------------------------------------------------------
__global__ __launch_bounds__(256)
void finalize(const float* __restrict__ avePart, const float* __restrict__ outPart,
              const float* __restrict__ b_lin, const float* __restrict__ b_lin_reg,
              float* __restrict__ out)
{
    const int idx = blockIdx.x * 256 + threadIdx.x;   // 2*512*3072
    const int c = idx % 3072;
    const int r = (idx / 3072) & 511;
    const int g = idx / (3072 * 512);
    float v;
    if (c < 1024) {
        v = 0.f;
        #pragma unroll
        for (int s = 0; s < 4; ++s)
            v += avePart[(size_t)s * 1048576 + (size_t)g * 524288 + r * 1024 + c];
    } else {
        const int cc = c - 1024;
        v = (g ? b_lin_reg : b_lin)[cc];
        #pragma unroll
        for (int s = 0; s < 4; ++s)
            v += outPart[(size_t)s * 2097152 + (size_t)g * 1048576 + r * 2048 + cc];
    }
    out[idx] = v;
}

extern "C" void kernel_launch(void* const* d_in, const int* in_sizes, int n_in,
                              void* d_out, int out_size, void* d_ws, size_t ws_size,
                              hipStream_t stream)
{
    const float* x_cls     = (const float*)d_in[0];
    const float* x_reg     = (const float*)d_in[1];
    const float* cls_score = (const float*)d_in[2];
    const float* W_q_cls   = (const float*)d_in[4];
    const float* W_kv_cls  = (const float*)d_in[5];
    const float* W_q_reg   = (const float*)d_in[6];
    const float* W_kv_reg  = (const float*)d_in[7];
    const float* W_lin     = (const float*)d_in[8];
    const float* b_lin     = (const float*)d_in[9];
    const float* W_lin_reg = (const float*)d_in[10];
    const float* b_lin_reg = (const float*)d_in[11];
    float* out = (float*)d_out;

    if (ws_size < (size_t)124 * 1048576) return;

    // Workspace overlay (MiB offsets), peak 108 MiB:
    char* W = (char*)d_ws;
    auto at = [&](size_t mb) { return (void*)(W + mb * 1048576); };
    _Float16* WlinT   = (_Float16*)at(0);    // prep -> M8                 [0,16)
    _Float16* vT      = (_Float16*)at(16);   // M1 -> M3                   [16,24)
    _Float16* x_ori   = (_Float16*)at(24);   // M1 -> build_xcat           [24,26)
    _Float16* w_c     = (_Float16*)at(26);   // sb2 -> M3                  [26,28)
    _Float16* w_r     = (_Float16*)at(28);   //                            [28,30)
    _Float16* qn      = (_Float16*)at(30);   // M1 -> M2                   [30,32)
    float*    simPart = (float*)at(32);      // M2 -> sb2                  [32,40)
    float*    outPart = (float*)at(32);      // M8 -> finalize (sim dead)  [32,64)
    _Float16* kn      = (_Float16*)at(40);   // M1 -> M2                   [40,48)
    _Float16* vn      = (_Float16*)at(48);   // M1 -> M2                   [48,56)
    _Float16* attn_h  = (_Float16*)at(40);   // sb2 -> M3 (kn/vn dead)     [40,56)
    _Float16* xbf     = (_Float16*)at(56);   // cast -> M1                 [56,64)
    _Float16* WqT     = (_Float16*)at(64);   // prep -> M1                 [64,68)
    _Float16* xcat16  = (_Float16*)at(64);   // build_xcat -> M8 (WqT dead)[64,68)
    _Float16* WkvT    = (_Float16*)at(68);   // prep -> M1                 [68,76)
    _Float16* S16     = (_Float16*)at(76);   // M2 -> sb2                  [76,108)
    float*    xcatPart= (float*)at(76);      // M3 -> build_xcat (S16 dead)[76,92)
    float*    avePart = (float*)at(92);      // M3 -> finalize             [92,108)

    // Phase 1: prep
    cast_f2h<<<dim3(2048, 2), 256, 0, stream>>>(x_cls, x_reg, xbf, 524288);
    prep_transpose<<<dim3(64, 64, 6), 256, 0, stream>>>(
        W_q_cls, W_q_reg, W_kv_cls, W_kv_reg, W_lin, W_lin_reg, WqT, WkvT, WlinT);

    // Phase 2 (M1): q-proj + kv-proj, both with fused L2-norm epilogues that
    // write qn / kn / vn / vT / x_ori directly (phase3 eliminated).
    {
        GD q  = mkgd(xbf, WqT, qn, nullptr,
                     0, 2097152, 0, 1048576, 0, 0, 0,
                     1024, 1024, 1024, 1024, 1, 0, 0, 1, 0, 0, 8, 2, 1.f);
        q.normMode = 1;
        GD kv = mkgd(xbf, WkvT, kn, nullptr,
                     0, 2097152, 0, 2097152, 0, 0, 0,
                     1024, 1024, 1024, 1024, 1, 0, 0, 1, 0, 0, 16, 8, 1.f);
        kv.normMode = 2; kv.vnp = vn; kv.vtp = vT; kv.xop = x_ori;
        hgemm3<<<dim3(16, 8, 4), 512, 0, stream>>>(q, kv, 2);
    }

    // Phase 4 (M2): v-sim (SK=1, fp32 direct) + scores (z=16, fp16)
    {
        GD vs = mkgd(vn, vn, simPart, nullptr,
                     0, 2097152, 0, 2097152, 0, 0, 1048576,
                     1024, 1024, 2048, 1024, 1, 0, 0, 0, 0, 0, 16, 2, 0.125f);
        GD sc = mkgd(qn, kn, S16, cls_score,
                     128, 524288, 128, 2097152, 0, 1048576, 8388608,
                     1024, 1024, 2048, 128, 1, 7, 3, 0, 1, 2, 16, 2, 25.f);
        hgemm3<<<dim3(16, 2, 18), 512, 0, stream>>>(vs, sc, 2);
    }

    // Phase 5: fused dual softmax + blend + head-mean + round2 weights
    sb2_kernel<<<512, 256, 0, stream>>>(S16, simPart, attn_h, w_c, w_r);

    // Phase 6 (M3): attn@V (AHX, SK=4) + ave (SK=4), both fp32 partials
    {
        GD av = mkgd(attn_h, vT, xcatPart, nullptr,
                     1048576, 0, 0, 2097152, 1048576, 0, 524288,
                     2048, 2048, 1024, 2048, 4, 0, 0, 1, 0, 0, 8, 2, 1.f);
        GD ae = mkgd(w_c, vT, avePart, nullptr,
                     0, 1048576, 0, 2097152, 1048576, 0, 524288,
                     2048, 2048, 1024, 2048, 4, 0, 0, 0, 0, 0, 8, 2, 1.f);
        hgemm3<<<dim3(8, 2, 16), 512, 0, stream>>>(av, ae, 8);
    }

    // Phase 7: xcat assembly (4-way reduce + x_ori)
    build_xcat<<<8192, 256, 0, stream>>>(xcatPart, x_ori, xcat16);

    // Phase 8 (M8): out-linears (SK=4, fp32 partials)
    {
        GD ol = mkgd(xcat16, WlinT, outPart, nullptr,
                     0, 1048576, 0, 4194304, 2097152, 0, 1048576,
                     2048, 2048, 2048, 2048, 4, 0, 0, 0, 0, 0, 16, 2, 1.f);
        hgemm3<<<dim3(16, 2, 8), 512, 0, stream>>>(ol, ol, 8);
    }

    // Phase 9: write d_out
    finalize<<<12288, 256, 0, stream>>>(avePart, outPart, b_lin, b_lin_reg, out);
}

// Round 5
// 280.661 us; speedup vs baseline: 1.0898x; 1.0547x over previous
//
#include <hip/hip_runtime.h>

typedef _Float16 half8 __attribute__((ext_vector_type(8)));
typedef _Float16 half4v __attribute__((ext_vector_type(4)));
typedef float f32x4 __attribute__((ext_vector_type(4)));

// async global->LDS, 16 B per lane; LDS dest is wave-uniform base + lane*16
#define GLD16(gptr, lptr) \
    __builtin_amdgcn_global_load_lds((const __attribute__((address_space(1))) void*)(gptr), \
                                     (__attribute__((address_space(3))) void*)(lptr), 16, 0, 0)

// s_waitcnt immediates: vmcnt [3:0]|[15:14], expcnt [6:4], lgkmcnt [11:8]
#define WAIT_VM3   0x0F73  // vmcnt(3)
#define WAIT_VM0   0x0F70  // vmcnt(0)
#define WAIT_LGKM0 0xC07F  // lgkmcnt(0)

// ---------------------------------------------------------------------------
// GEMM descriptor (two independent GEMMs share one launch via blockIdx.z).
// zz = bz / SK; s = bz % SK; h = ahx ? bx : zz & hmask; g = ahx ? zz : zz>>hshift.
// A += h*sAh + g*sAg; B += h*sBh + g*sBg; Coff = s*sSplit + h*sCh + g*sCg.
// normMode: 0 plain; 1 q-norm; 2 kv-norm (+vn/vT/x_ori).
// ---------------------------------------------------------------------------
struct GD {
    const _Float16* A; const _Float16* B; void* C;
    const float* colScale;
    _Float16 *vnp, *vtp, *xop;
    long sAh, sAg, sBh, sBg, sSplit, sCh, sCg;
    int lda, ldb, ldc, K, SK, hmask, hshift;
    int ahx, outHalf, csMode, nx, ny, normMode;   // csMode: 0 none, 1 always, 2 g==0
    float alpha;
};

// ---------------------------------------------------------------------------
// hgemm3: 256x128 tile, BK=32, 512 threads (8 waves of 64x64, 4M x 2N),
// 3-slot LDS ring (72 KB -> 2 blocks/CU), depth-2 prefetch, counted vmcnt.
//
// Round-5 changes:
//  (a) XCD-chunked bijective blockIdx swizzle (T1) when the launched x*y
//      rectangle is fully active (NWG % 8 == 0 for all swizzled grids):
//      each XCD gets a contiguous run of tiles -> A-panel fetched once per
//      XCD, B row-panel stays L2-resident.  Partially-active slices (the
//      small q GEMM) keep the identity mapping (stays spread over XCDs).
//  (b) K-step split into two 8-MFMA clusters with s_setprio(1) around each
//      (T5-enabler); P2's ds_reads + the counted vmcnt issue between the
//      clusters; sched_barrier(0) after each waitcnt pins the schedule.
//
// Staging: LDS row-major [row][32 halves]; each GLD16 = 16 rows x 64 B,
// 4 lanes per aligned line (coalesced). Bank-conflict fix (both-sides):
// LDS 16-B slot s of row r holds global chunk c = s ^ ((r>>1)&3); frag reads
// use slot = kq ^ ((lm>>1)&3)  (SQ_LDS_BANK_CONFLICT == 0 measured).
// Ring safety: stage(t+2) targets slot (t-1)%3 whose readers retired
// (lgkmcnt(0)) before the barrier that opened step t.
// ---------------------------------------------------------------------------
__global__ __launch_bounds__(512, 4)
void hgemm3(GD d0, GD d1, int zSplit)
{
    const bool second = (int)blockIdx.z >= zSplit;
    const GD& d = second ? d1 : d0;
    const int bz = second ? (int)blockIdx.z - zSplit : (int)blockIdx.z;

    // (a) XCD swizzle on the (x,y) plane
    const int GX = gridDim.x, GY = gridDim.y;
    int bx = (int)blockIdx.x, by = (int)blockIdx.y;
    {
        const int NWG = GX * GY;
        if (d.nx * d.ny == NWG) {             // fully-active rectangle only
            const int lin = by * GX + bx;
            const int q8 = NWG >> 3;          // NWG % 8 == 0 for these grids
            const int wg = (lin & 7) * q8 + (lin >> 3);
            bx = wg % GX; by = wg / GX;
        }
    }
    if (bx >= d.nx || by >= d.ny) return;

    __shared__ uint4 smem[4608];          // 72 KB: 3 ring slots x 24 KB
    char* sb = (char*)smem;
    const int tid = threadIdx.x;
    const int w = tid >> 6, l = tid & 63;
    const int m0 = by << 8, n0 = bx << 7;
    const int wm = (w >> 1) << 6, wn = (w & 1) << 6;
    const int kq = l >> 4, lm = l & 15;

    const int zz = bz / d.SK, s = bz - zz * d.SK;
    const int h = d.ahx ? bx : (zz & d.hmask);
    const int g = d.ahx ? zz : (zz >> d.hshift);
    const _Float16* A = d.A + (long)h * d.sAh + (long)g * d.sAg;
    const _Float16* B = d.B + (long)h * d.sBh + (long)g * d.sBg;
    const long Coff = (long)s * d.sSplit + (long)h * d.sCh + (long)g * d.sCg;
    const int kper = d.K / d.SK, kbeg = s * kper;
    const int NT = kper >> 5;

    // staging: each instr = 16 rows x 64 B, 4 lanes per full line.
    const int rS = (w << 4) + (l >> 2);
    const int cS = (l & 3) ^ ((l >> 3) & 3);      // slot ^ ((rS>>1)&3)
    const _Float16* gA0 = A + (long)(m0 + rS) * d.lda + kbeg + cS * 8;
    const _Float16* gB0 = B + (long)(n0 + rS) * d.ldb + kbeg + cS * 8;
    const int lo = w * 1024 + l * 16;

    auto stage = [&](int t) {
        char* dst = sb + (t % 3) * 24576;
        GLD16(gA0 + t * 32,                     dst + lo);           // A rows 0-127
        GLD16(gA0 + (long)128 * d.lda + t * 32, dst + 8192 + lo);    // A rows 128-255
        GLD16(gB0 + t * 32,                     dst + 16384 + lo);   // B rows 0-127
    };

    f32x4 acc[4][4] = {};
    stage(0);
    if (NT > 1) stage(1);
    if (NT > 1) __builtin_amdgcn_s_waitcnt(WAIT_VM3);
    else        __builtin_amdgcn_s_waitcnt(WAIT_VM0);
    __builtin_amdgcn_s_barrier();

    const int sw16 = ((kq ^ ((lm >> 1) & 3)) << 4);   // swizzled 16-B slot
    for (int t = 0; t < NT; ++t) {
        const char* cb = sb + (t % 3) * 24576;
        const char* pa = cb + (wm + lm) * 64 + sw16;
        const char* pb = cb + 16384 + (wn + lm) * 64 + sw16;
        half8 af[4], bfr[4];
        // ---- P1: loads for cluster 1 + stage issue ----
        bfr[0] = *(const half8*)(pb + 0 * 1024);
        bfr[1] = *(const half8*)(pb + 1 * 1024);
        #pragma unroll
        for (int i = 0; i < 4; ++i) af[i] = *(const half8*)(pa + i * 1024);
        if (t + 2 < NT) stage(t + 2);
        __builtin_amdgcn_s_waitcnt(WAIT_LGKM0);
        __builtin_amdgcn_sched_barrier(0);
        __builtin_amdgcn_s_setprio(1);
        #pragma unroll
        for (int mi = 0; mi < 4; ++mi) {
            acc[mi][0] = __builtin_amdgcn_mfma_f32_16x16x32_f16(af[mi], bfr[0], acc[mi][0], 0, 0, 0);
            acc[mi][1] = __builtin_amdgcn_mfma_f32_16x16x32_f16(af[mi], bfr[1], acc[mi][1], 0, 0, 0);
        }
        __builtin_amdgcn_s_setprio(0);
        // ---- P2: loads for cluster 2 + counted vmcnt ----
        bfr[2] = *(const half8*)(pb + 2 * 1024);
        bfr[3] = *(const half8*)(pb + 3 * 1024);
        if (t + 2 < NT)      __builtin_amdgcn_s_waitcnt(WAIT_VM3);
        else if (t + 1 < NT) __builtin_amdgcn_s_waitcnt(WAIT_VM0);
        __builtin_amdgcn_s_waitcnt(WAIT_LGKM0);
        __builtin_amdgcn_sched_barrier(0);
        __builtin_amdgcn_s_setprio(1);
        #pragma unroll
        for (int mi = 0; mi < 4; ++mi) {
            acc[mi][2] = __builtin_amdgcn_mfma_f32_16x16x32_f16(af[mi], bfr[2], acc[mi][2], 0, 0, 0);
            acc[mi][3] = __builtin_amdgcn_mfma_f32_16x16x32_f16(af[mi], bfr[3], acc[mi][3], 0, 0, 0);
        }
        __builtin_amdgcn_s_setprio(0);
        __builtin_amdgcn_s_barrier();                 // tile t+1 landed+visible
    }

    // C/D layout: col = lane&15, row = (lane>>4)*4 + reg
    if (d.normMode == 0) {
        const int rbase = m0 + wm + kq * 4;
        #pragma unroll
        for (int mi = 0; mi < 4; ++mi) {
            #pragma unroll
            for (int ni = 0; ni < 4; ++ni) {
                const int col = n0 + wn + ni * 16 + lm;
                float cs = d.alpha;
                if (d.csMode == 1 || (d.csMode == 2 && g == 0)) cs *= d.colScale[col];
                #pragma unroll
                for (int r = 0; r < 4; ++r) {
                    const long row = rbase + mi * 16 + r;
                    const float v = acc[mi][ni][r] * cs;
                    const long off = Coff + row * d.ldc + col;
                    if (d.outHalf) ((_Float16*)d.C)[off] = (_Float16)v;
                    else           ((float*)d.C)[off] = v;
                }
            }
        }
        return;
    }

    // ---- fused L2-norm epilogue (block cols = exactly one 128-dim head) ----
    float* part = (float*)sb;                 // part[2][256]
    float ssq[4][4];
    #pragma unroll
    for (int mi = 0; mi < 4; ++mi)
        #pragma unroll
        for (int r = 0; r < 4; ++r) {
            float sq = 0.f;
            #pragma unroll
            for (int ni = 0; ni < 4; ++ni) { const float v = acc[mi][ni][r]; sq += v * v; }
            sq += __shfl_xor(sq, 1, 64);
            sq += __shfl_xor(sq, 2, 64);
            sq += __shfl_xor(sq, 4, 64);
            sq += __shfl_xor(sq, 8, 64);
            ssq[mi][r] = sq;
        }
    if (lm == 0) {
        #pragma unroll
        for (int mi = 0; mi < 4; ++mi)
            #pragma unroll
            for (int r = 0; r < 4; ++r)
                part[(w & 1) * 256 + wm + kq * 4 + mi * 16 + r] = ssq[mi][r];
    }
    __syncthreads();

    #pragma unroll
    for (int mi = 0; mi < 4; ++mi) {
        #pragma unroll
        for (int r = 0; r < 4; ++r) {
            const int rl = wm + kq * 4 + mi * 16 + r;
            const float inv = rsqrtf(part[rl] + part[256 + rl]);
            const long rg = m0 + rl;
            if (d.normMode == 1) {
                #pragma unroll
                for (int ni = 0; ni < 4; ++ni) {
                    const int col = n0 + wn + ni * 16 + lm;
                    ((_Float16*)d.C)[(long)g * 524288 + rg * 1024 + col] =
                        (_Float16)(acc[mi][ni][r] * inv);
                }
            } else if (n0 < 1024) {           // K half -> kn
                #pragma unroll
                for (int ni = 0; ni < 4; ++ni) {
                    const int col = n0 + wn + ni * 16 + lm;
                    ((_Float16*)d.C)[(long)g * 2097152 + rg * 1024 + col] =
                        (_Float16)(acc[mi][ni][r] * inv);
                }
            } else {                          // V half -> vn + x_ori
                #pragma unroll
                for (int ni = 0; ni < 4; ++ni) {
                    const int nL = n0 - 1024 + wn + ni * 16 + lm;
                    d.vnp[(long)g * 2097152 + rg * 1024 + nL] =
                        (_Float16)(acc[mi][ni][r] * inv);
                    if (rg < 512)
                        d.xop[(long)g * 524288 + rg * 1024 + nL] = (_Float16)acc[mi][ni][r];
                }
            }
        }
    }
    // vT raw transposed store (V half)
    if (d.normMode == 2 && n0 >= 1024) {
        #pragma unroll
        for (int mi = 0; mi < 4; ++mi)
            #pragma unroll
            for (int ni = 0; ni < 4; ++ni) {
                const int nL = n0 - 1024 + wn + ni * 16 + lm;
                half4v t;
                t.x = (_Float16)acc[mi][ni][0]; t.y = (_Float16)acc[mi][ni][1];
                t.z = (_Float16)acc[mi][ni][2]; t.w = (_Float16)acc[mi][ni][3];
                *(half4v*)(d.vtp + (long)g * 2097152 + (long)nL * 2048
                           + m0 + wm + kq * 4 + mi * 16) = t;
            }
    }
}

static GD mkgd(const _Float16* A, const _Float16* B, void* C, const float* cscale,
               long sAh, long sAg, long sBh, long sBg, long sSplit, long sCh, long sCg,
               int lda, int ldb, int ldc, int K, int SK, int hmask, int hshift,
               int ahx, int outHalf, int csMode, int nx, int ny, float alpha)
{
    GD d; d.A=A; d.B=B; d.C=C; d.colScale=cscale;
    d.vnp=nullptr; d.vtp=nullptr; d.xop=nullptr;
    d.sAh=sAh; d.sAg=sAg; d.sBh=sBh; d.sBg=sBg; d.sSplit=sSplit; d.sCh=sCh; d.sCg=sCg;
    d.lda=lda; d.ldb=ldb; d.ldc=ldc; d.K=K; d.SK=SK; d.hmask=hmask; d.hshift=hshift;
    d.ahx=ahx; d.outHalf=outHalf; d.csMode=csMode; d.nx=nx; d.ny=ny; d.normMode=0;
    d.alpha=alpha;
    return d;
}

// ---------------------------------------------------------------------------
// prep_all: grid (64,64,7). z<6: weight transposes (f32 -> f16 T);
// z==6: fp32->fp16 cast of x_cls|x_reg (lin = by*64+bx picks slice).
// ---------------------------------------------------------------------------
__global__ __launch_bounds__(256)
void prep_all(const float* __restrict__ x_cls, const float* __restrict__ x_reg,
              const float* __restrict__ Wq_c, const float* __restrict__ Wq_r,
              const float* __restrict__ Wkv_c, const float* __restrict__ Wkv_r,
              const float* __restrict__ Wl_c, const float* __restrict__ Wl_r,
              _Float16* __restrict__ xbf,
              _Float16* __restrict__ WqT, _Float16* __restrict__ WkvT,
              _Float16* __restrict__ WlinT)
{
    const int z = blockIdx.z;
    if (z == 6) {
        const int lin = blockIdx.y * 64 + blockIdx.x;    // [0,4096)
        const int which = lin >> 11;
        const int i = (lin & 2047) * 256 + threadIdx.x;  // float4 index
        const float* s = which ? x_reg : x_cls;
        const float4 v = ((const float4*)s)[i];
        half4v o;
        o.x = (_Float16)v.x; o.y = (_Float16)v.y; o.z = (_Float16)v.z; o.w = (_Float16)v.w;
        ((half4v*)(xbf + (size_t)which * 2097152))[i] = o;
        return;
    }
    __shared__ float t[32][33];
    const float* src; _Float16* dst; int ldsrc, lddst, nx, ky;
    switch (z) {
        case 0: src=Wq_c;  dst=WqT;            ldsrc=1024; lddst=1024; nx=32; ky=32; break;
        case 1: src=Wq_r;  dst=WqT+1048576;    ldsrc=1024; lddst=1024; nx=32; ky=32; break;
        case 2: src=Wkv_c; dst=WkvT;           ldsrc=2048; lddst=1024; nx=64; ky=32; break;
        case 3: src=Wkv_r; dst=WkvT+2097152;   ldsrc=2048; lddst=1024; nx=64; ky=32; break;
        case 4: src=Wl_c;  dst=WlinT;          ldsrc=2048; lddst=2048; nx=64; ky=64; break;
        default:src=Wl_r;  dst=WlinT+4194304;  ldsrc=2048; lddst=2048; nx=64; ky=64; break;
    }
    if ((int)blockIdx.x >= nx || (int)blockIdx.y >= ky) return;
    const int n0 = blockIdx.x << 5, k0 = blockIdx.y << 5;
    const int tx = threadIdx.x & 31, ty = threadIdx.x >> 5;
    #pragma unroll
    for (int j = ty; j < 32; j += 8)
        t[j][tx] = src[(size_t)(k0 + j) * ldsrc + n0 + tx];
    __syncthreads();
    #pragma unroll
    for (int j = ty; j < 32; j += 8)
        dst[(size_t)(n0 + j) * lddst + k0 + tx] = (_Float16)t[tx][j];
}

// ---------------------------------------------------------------------------
// Block reduce (256 threads, 4 waves). OP: 0 sum, 1 max
// ---------------------------------------------------------------------------
template<int OP>
__device__ __forceinline__ float bred(float v, float* lds)
{
    #pragma unroll
    for (int o = 32; o > 0; o >>= 1) {
        const float u = __shfl_xor(v, o, 64);
        v = OP ? fmaxf(v, u) : v + u;
    }
    __syncthreads();
    if ((threadIdx.x & 63) == 0) lds[threadIdx.x >> 6] = v;
    __syncthreads();
    return OP ? fmaxf(fmaxf(lds[0], lds[1]), fmaxf(lds[2], lds[3]))
              : lds[0] + lds[1] + lds[2] + lds[3];
}

// ---------------------------------------------------------------------------
// Fused: per q row — dual softmax per head + blend -> fp16 attn + head-mean,
// then round-2 masked renorm weights.
// S16 [16][512][2048] fp16 (0-7 cls, 8-15 reg); simPart [2][512][2048] f32.
// ---------------------------------------------------------------------------
__global__ __launch_bounds__(256)
void sb2_kernel(const _Float16* __restrict__ S16, const float* __restrict__ simPart,
                _Float16* __restrict__ attn,
                _Float16* __restrict__ wc, _Float16* __restrict__ wr)
{
    __shared__ float lds[4];
    const int q = blockIdx.x, t = threadIdx.x;
    float asum[8] = {};
    for (int hh = 0; hh < 8; ++hh) {
        const size_t rb = (size_t)(hh * 512 + q) * 2048;
        float vc[8], vr[8];
        float mc = -1e30f, mr = -1e30f;
        #pragma unroll
        for (int j = 0; j < 8; ++j) {
            vc[j] = (float)S16[rb + t + 256 * j];
            vr[j] = (float)S16[8388608 + rb + t + 256 * j];
            mc = fmaxf(mc, vc[j]); mr = fmaxf(mr, vr[j]);
        }
        mc = bred<1>(mc, lds);
        mr = bred<1>(mr, lds);
        float sc = 0.f, sr = 0.f;
        #pragma unroll
        for (int j = 0; j < 8; ++j) {
            vc[j] = expf(vc[j] - mc); sc += vc[j];
            vr[j] = expf(vr[j] - mr); sr += vr[j];
        }
        sc = bred<0>(sc, lds);
        sr = bred<0>(sr, lds);
        const float ic = 0.5f / sc, ir = 0.5f / sr;
        #pragma unroll
        for (int j = 0; j < 8; ++j) {
            const float a = vc[j] * ic + vr[j] * ir;
            attn[rb + t + 256 * j] = (_Float16)a;
            asum[j] += a;
        }
    }
    float mx = -1e30f;
    #pragma unroll
    for (int j = 0; j < 8; ++j) { asum[j] *= 0.125f; mx = fmaxf(mx, asum[j]); }
    mx = bred<1>(mx, lds);
    float em[8], emo[8];
    float s1 = 0.f, s2 = 0.f;
    const size_t qb = (size_t)q * 2048;
    #pragma unroll
    for (int j = 0; j < 8; ++j) {
        const size_t o = qb + t + 256 * j;
        const float sim = simPart[o];
        const float reg = simPart[1048576 + o];
        const float e = expf(asum[j] - mx);
        const float m  = sim > 0.75f ? 1.f : 0.f;
        const float mo = reg > 0.99f ? 1.f : 0.f;
        em[j] = e * m; emo[j] = e * m * mo;
        s1 += em[j]; s2 += emo[j];
    }
    s1 = bred<0>(s1, lds);
    s2 = bred<0>(s2, lds);
    const float i1 = 1.f / s1, i2 = 1.f / s2;
    #pragma unroll
    for (int j = 0; j < 8; ++j) {
        wc[qb + t + 256 * j] = (_Float16)(em[j] * i1);
        wr[qb + t + 256 * j] = (_Float16)(emo[j] * i2);
    }
}

// ---------------------------------------------------------------------------
// xcat16 [2][512][2048]: cols<1024 = 4-way reduce of fp16 attn@V partials,
// cols>=1024 = x_ori.
// ---------------------------------------------------------------------------
__global__ __launch_bounds__(256)
void build_xcat(const _Float16* __restrict__ xcatPart, const _Float16* __restrict__ x_ori,
                _Float16* __restrict__ xcat)
{
    const int idx = blockIdx.x * 256 + threadIdx.x;   // 2*512*2048
    const int j = idx & 2047;
    const int n = (idx >> 11) & 511;
    const int g = idx >> 20;
    _Float16 v;
    if (j < 1024) {
        float a = 0.f;
        #pragma unroll
        for (int s = 0; s < 4; ++s)
            a += (float)xcatPart[(size_t)s * 1048576 + (size_t)g * 524288 + n * 1024 + j];
        v = (_Float16)a;
    } else {
        v = x_ori[(size_t)g * 524288 + (size_t)n * 1024 + (j - 1024)];
    }
    xcat[idx] = v;
}

// ---------------------------------------------------------------------------
// finalize d_out [2][512][3072]: cols<1024 4-way avePart (f32) reduce;
// cols>=1024 4-way outPart (f32) reduce + bias.
// ---------------------------------------------------------------------------
__global__ __launch_bounds__(256)
void finalize(const float* __restrict__ avePart, const float* __restrict__ outPart,
              const float* __restrict__ b_lin, const float* __restrict__ b_lin_reg,
              float* __restrict__ out)
{
    const int idx = blockIdx.x * 256 + threadIdx.x;   // 2*512*3072
    const int c = idx % 3072;
    const int r = (idx / 3072) & 511;
    const int g = idx / (3072 * 512);
    float v;
    if (c < 1024) {
        v = 0.f;
        #pragma unroll
        for (int s = 0; s < 4; ++s)
            v += avePart[(size_t)s * 1048576 + (size_t)g * 524288 + r * 1024 + c];
    } else {
        const int cc = c - 1024;
        v = (g ? b_lin_reg : b_lin)[cc];
        #pragma unroll
        for (int s = 0; s < 4; ++s)
            v += outPart[(size_t)s * 2097152 + (size_t)g * 1048576 + r * 2048 + cc];
    }
    out[idx] = v;
}

extern "C" void kernel_launch(void* const* d_in, const int* in_sizes, int n_in,
                              void* d_out, int out_size, void* d_ws, size_t ws_size,
                              hipStream_t stream)
{
    const float* x_cls     = (const float*)d_in[0];
    const float* x_reg     = (const float*)d_in[1];
    const float* cls_score = (const float*)d_in[2];
    const float* W_q_cls   = (const float*)d_in[4];
    const float* W_kv_cls  = (const float*)d_in[5];
    const float* W_q_reg   = (const float*)d_in[6];
    const float* W_kv_reg  = (const float*)d_in[7];
    const float* W_lin     = (const float*)d_in[8];
    const float* b_lin     = (const float*)d_in[9];
    const float* W_lin_reg = (const float*)d_in[10];
    const float* b_lin_reg = (const float*)d_in[11];
    float* out = (float*)d_out;

    if (ws_size < (size_t)124 * 1048576) return;

    // Workspace overlay (MiB offsets):
    char* W = (char*)d_ws;
    auto at = [&](size_t mb) { return (void*)(W + mb * 1048576); };
    _Float16* WlinT   = (_Float16*)at(0);    // prep -> M8                 [0,16)
    _Float16* vT      = (_Float16*)at(16);   // M1 -> M3                   [16,24)
    _Float16* x_ori   = (_Float16*)at(24);   // M1 -> build_xcat           [24,26)
    _Float16* w_c     = (_Float16*)at(26);   // sb2 -> M3                  [26,28)
    _Float16* w_r     = (_Float16*)at(28);   //                            [28,30)
    _Float16* qn      = (_Float16*)at(30);   // M1 -> M2                   [30,32)
    float*    simPart = (float*)at(32);      // M2 -> sb2                  [32,40)
    float*    outPart = (float*)at(32);      // M8 -> finalize (sim dead)  [32,64)
    _Float16* kn      = (_Float16*)at(40);   // M1 -> M2                   [40,48)
    _Float16* vn      = (_Float16*)at(48);   // M1 -> M2                   [48,56)
    _Float16* attn_h  = (_Float16*)at(40);   // sb2 -> M3 (kn/vn dead)     [40,56)
    _Float16* xbf     = (_Float16*)at(56);   // prep -> M1                 [56,64)
    _Float16* WqT     = (_Float16*)at(64);   // prep -> M1                 [64,68)
    _Float16* xcat16  = (_Float16*)at(64);   // build_xcat -> M8 (WqT dead)[64,68)
    _Float16* WkvT    = (_Float16*)at(68);   // prep -> M1                 [68,76)
    _Float16* S16     = (_Float16*)at(76);   // M2 -> sb2                  [76,108)
    _Float16* xcatPart= (_Float16*)at(76);   // M3 -> build_xcat (S16 dead)[76,84)
    float*    avePart = (float*)at(84);      // M3 -> finalize             [84,100)

    // Phase 1: prep (cast + all transposes, one launch)
    prep_all<<<dim3(64, 64, 7), 256, 0, stream>>>(
        x_cls, x_reg, W_q_cls, W_q_reg, W_kv_cls, W_kv_reg, W_lin, W_lin_reg,
        xbf, WqT, WkvT, WlinT);

    // Phase 2 (M1): q-proj + kv-proj with fused L2-norm epilogues
    {
        GD q  = mkgd(xbf, WqT, qn, nullptr,
                     0, 2097152, 0, 1048576, 0, 0, 0,
                     1024, 1024, 1024, 1024, 1, 0, 0, 1, 0, 0, 8, 2, 1.f);
        q.normMode = 1;
        GD kv = mkgd(xbf, WkvT, kn, nullptr,
                     0, 2097152, 0, 2097152, 0, 0, 0,
                     1024, 1024, 1024, 1024, 1, 0, 0, 1, 0, 0, 16, 8, 1.f);
        kv.normMode = 2; kv.vnp = vn; kv.vtp = vT; kv.xop = x_ori;
        hgemm3<<<dim3(16, 8, 4), 512, 0, stream>>>(q, kv, 2);
    }

    // Phase 4 (M2): v-sim (fp32 direct) + scores (z=16, fp16)
    {
        GD vs = mkgd(vn, vn, simPart, nullptr,
                     0, 2097152, 0, 2097152, 0, 0, 1048576,
                     1024, 1024, 2048, 1024, 1, 0, 0, 0, 0, 0, 16, 2, 0.125f);
        GD sc = mkgd(qn, kn, S16, cls_score,
                     128, 524288, 128, 2097152, 0, 1048576, 8388608,
                     1024, 1024, 2048, 128, 1, 7, 3, 0, 1, 2, 16, 2, 25.f);
        hgemm3<<<dim3(16, 2, 18), 512, 0, stream>>>(vs, sc, 2);
    }

    // Phase 5: fused dual softmax + blend + head-mean + round2 weights
    sb2_kernel<<<512, 256, 0, stream>>>(S16, simPart, attn_h, w_c, w_r);

    // Phase 6 (M3): attn@V (AHX, SK=4, fp16 partials) + ave (SK=4, f32)
    {
        GD av = mkgd(attn_h, vT, xcatPart, nullptr,
                     1048576, 0, 0, 2097152, 1048576, 0, 524288,
                     2048, 2048, 1024, 2048, 4, 0, 0, 1, 1, 0, 8, 2, 1.f);
        GD ae = mkgd(w_c, vT, avePart, nullptr,
                     0, 1048576, 0, 2097152, 1048576, 0, 524288,
                     2048, 2048, 1024, 2048, 4, 0, 0, 0, 0, 0, 8, 2, 1.f);
        hgemm3<<<dim3(8, 2, 16), 512, 0, stream>>>(av, ae, 8);
    }

    // Phase 7: xcat assembly (4-way fp16 reduce + x_ori)
    build_xcat<<<8192, 256, 0, stream>>>(xcatPart, x_ori, xcat16);

    // Phase 8 (M8): out-linears (SK=4, fp32 partials)
    {
        GD ol = mkgd(xcat16, WlinT, outPart, nullptr,
                     0, 1048576, 0, 4194304, 2097152, 0, 1048576,
                     2048, 2048, 2048, 2048, 4, 0, 0, 0, 0, 0, 16, 2, 1.f);
        hgemm3<<<dim3(16, 2, 8), 512, 0, stream>>>(ol, ol, 8);
    }

    // Phase 9: write d_out
    finalize<<<12288, 256, 0, stream>>>(avePart, outPart, b_lin, b_lin_reg, out);
}

// Round 6
// 270.136 us; speedup vs baseline: 1.1323x; 1.0390x over previous
//
#include <hip/hip_runtime.h>

typedef _Float16 half8 __attribute__((ext_vector_type(8)));
typedef _Float16 half4v __attribute__((ext_vector_type(4)));
typedef float f32x4 __attribute__((ext_vector_type(4)));

// async global->LDS, 16 B per lane; LDS dest is wave-uniform base + lane*16
#define GLD16(gptr, lptr) \
    __builtin_amdgcn_global_load_lds((const __attribute__((address_space(1))) void*)(gptr), \
                                     (__attribute__((address_space(3))) void*)(lptr), 16, 0, 0)

// s_waitcnt immediates: vmcnt [3:0]|[15:14], expcnt [6:4], lgkmcnt [11:8]
#define WAIT_VM3   0x0F73  // vmcnt(3)
#define WAIT_VM0   0x0F70  // vmcnt(0)
#define WAIT_LGKM0 0xC07F  // lgkmcnt(0)

// ---------------------------------------------------------------------------
// GEMM descriptor (two independent GEMMs share one launch via blockIdx.z).
// zz = bz / SK; s = bz % SK; h = ahx ? bx : zz & hmask; g = ahx ? zz : zz>>hshift.
// A += h*sAh + g*sAg; B += h*sBh + g*sBg; Coff = s*sSplit + h*sCh + g*sCg.
// normMode: 0 plain; 1 q-norm; 2 kv-norm (+vn/vT/x_ori).
// ---------------------------------------------------------------------------
struct GD {
    const _Float16* A; const _Float16* B; void* C;
    const float* colScale;
    _Float16 *vnp, *vtp, *xop;
    long sAh, sAg, sBh, sBg, sSplit, sCh, sCg;
    int lda, ldb, ldc, K, SK, hmask, hshift;
    int ahx, outHalf, csMode, nx, ny, normMode;   // csMode: 0 none, 1 always, 2 g==0
    float alpha;
};

// ---------------------------------------------------------------------------
// hgemm3: 256x128 tile, BK=32, 512 threads (8 waves of 64x64, 4M x 2N),
// 3-slot LDS ring (72 KB -> 2 blocks/CU), depth-2 prefetch, counted vmcnt.
// K-step split into two 8-MFMA clusters with setprio (neutral, kept).
// XCD swizzle REVERTED (round-5 measurement: FETCH +5 MB, perf null).
//
// Staging: LDS row-major [row][32 halves]; each GLD16 = 16 rows x 64 B,
// 4 lanes per aligned line (coalesced). Bank-conflict fix (both-sides):
// LDS 16-B slot s of row r holds global chunk c = s ^ ((r>>1)&3); frag reads
// use slot = kq ^ ((lm>>1)&3)  (SQ_LDS_BANK_CONFLICT == 0 measured).
// Ring safety: stage(t+2) targets slot (t-1)%3 whose readers retired
// (lgkmcnt(0)) before the barrier that opened step t.
// ---------------------------------------------------------------------------
__global__ __launch_bounds__(512, 4)
void hgemm3(GD d0, GD d1, int zSplit)
{
    const bool second = (int)blockIdx.z >= zSplit;
    const GD& d = second ? d1 : d0;
    const int bz = second ? (int)blockIdx.z - zSplit : (int)blockIdx.z;
    const int bx = (int)blockIdx.x, by = (int)blockIdx.y;
    if (bx >= d.nx || by >= d.ny) return;

    __shared__ uint4 smem[4608];          // 72 KB: 3 ring slots x 24 KB
    char* sb = (char*)smem;
    const int tid = threadIdx.x;
    const int w = tid >> 6, l = tid & 63;
    const int m0 = by << 8, n0 = bx << 7;
    const int wm = (w >> 1) << 6, wn = (w & 1) << 6;
    const int kq = l >> 4, lm = l & 15;

    const int zz = bz / d.SK, s = bz - zz * d.SK;
    const int h = d.ahx ? bx : (zz & d.hmask);
    const int g = d.ahx ? zz : (zz >> d.hshift);
    const _Float16* A = d.A + (long)h * d.sAh + (long)g * d.sAg;
    const _Float16* B = d.B + (long)h * d.sBh + (long)g * d.sBg;
    const long Coff = (long)s * d.sSplit + (long)h * d.sCh + (long)g * d.sCg;
    const int kper = d.K / d.SK, kbeg = s * kper;
    const int NT = kper >> 5;

    // staging: each instr = 16 rows x 64 B, 4 lanes per full line.
    const int rS = (w << 4) + (l >> 2);
    const int cS = (l & 3) ^ ((l >> 3) & 3);      // slot ^ ((rS>>1)&3)
    const _Float16* gA0 = A + (long)(m0 + rS) * d.lda + kbeg + cS * 8;
    const _Float16* gB0 = B + (long)(n0 + rS) * d.ldb + kbeg + cS * 8;
    const int lo = w * 1024 + l * 16;

    auto stage = [&](int t) {
        char* dst = sb + (t % 3) * 24576;
        GLD16(gA0 + t * 32,                     dst + lo);           // A rows 0-127
        GLD16(gA0 + (long)128 * d.lda + t * 32, dst + 8192 + lo);    // A rows 128-255
        GLD16(gB0 + t * 32,                     dst + 16384 + lo);   // B rows 0-127
    };

    f32x4 acc[4][4] = {};
    stage(0);
    if (NT > 1) stage(1);
    if (NT > 1) __builtin_amdgcn_s_waitcnt(WAIT_VM3);
    else        __builtin_amdgcn_s_waitcnt(WAIT_VM0);
    __builtin_amdgcn_s_barrier();

    const int sw16 = ((kq ^ ((lm >> 1) & 3)) << 4);   // swizzled 16-B slot
    for (int t = 0; t < NT; ++t) {
        const char* cb = sb + (t % 3) * 24576;
        const char* pa = cb + (wm + lm) * 64 + sw16;
        const char* pb = cb + 16384 + (wn + lm) * 64 + sw16;
        half8 af[4], bfr[4];
        // ---- P1: loads for cluster 1 + stage issue ----
        bfr[0] = *(const half8*)(pb + 0 * 1024);
        bfr[1] = *(const half8*)(pb + 1 * 1024);
        #pragma unroll
        for (int i = 0; i < 4; ++i) af[i] = *(const half8*)(pa + i * 1024);
        if (t + 2 < NT) stage(t + 2);
        __builtin_amdgcn_s_waitcnt(WAIT_LGKM0);
        __builtin_amdgcn_sched_barrier(0);
        __builtin_amdgcn_s_setprio(1);
        #pragma unroll
        for (int mi = 0; mi < 4; ++mi) {
            acc[mi][0] = __builtin_amdgcn_mfma_f32_16x16x32_f16(af[mi], bfr[0], acc[mi][0], 0, 0, 0);
            acc[mi][1] = __builtin_amdgcn_mfma_f32_16x16x32_f16(af[mi], bfr[1], acc[mi][1], 0, 0, 0);
        }
        __builtin_amdgcn_s_setprio(0);
        // ---- P2: loads for cluster 2 + counted vmcnt ----
        bfr[2] = *(const half8*)(pb + 2 * 1024);
        bfr[3] = *(const half8*)(pb + 3 * 1024);
        if (t + 2 < NT)      __builtin_amdgcn_s_waitcnt(WAIT_VM3);
        else if (t + 1 < NT) __builtin_amdgcn_s_waitcnt(WAIT_VM0);
        __builtin_amdgcn_s_waitcnt(WAIT_LGKM0);
        __builtin_amdgcn_sched_barrier(0);
        __builtin_amdgcn_s_setprio(1);
        #pragma unroll
        for (int mi = 0; mi < 4; ++mi) {
            acc[mi][2] = __builtin_amdgcn_mfma_f32_16x16x32_f16(af[mi], bfr[2], acc[mi][2], 0, 0, 0);
            acc[mi][3] = __builtin_amdgcn_mfma_f32_16x16x32_f16(af[mi], bfr[3], acc[mi][3], 0, 0, 0);
        }
        __builtin_amdgcn_s_setprio(0);
        __builtin_amdgcn_s_barrier();                 // tile t+1 landed+visible
    }

    // C/D layout: col = lane&15, row = (lane>>4)*4 + reg
    if (d.normMode == 0) {
        const int rbase = m0 + wm + kq * 4;
        #pragma unroll
        for (int mi = 0; mi < 4; ++mi) {
            #pragma unroll
            for (int ni = 0; ni < 4; ++ni) {
                const int col = n0 + wn + ni * 16 + lm;
                float cs = d.alpha;
                if (d.csMode == 1 || (d.csMode == 2 && g == 0)) cs *= d.colScale[col];
                #pragma unroll
                for (int r = 0; r < 4; ++r) {
                    const long row = rbase + mi * 16 + r;
                    const float v = acc[mi][ni][r] * cs;
                    const long off = Coff + row * d.ldc + col;
                    if (d.outHalf) ((_Float16*)d.C)[off] = (_Float16)v;
                    else           ((float*)d.C)[off] = v;
                }
            }
        }
        return;
    }

    // ---- fused L2-norm epilogue (block cols = exactly one 128-dim head) ----
    float* part = (float*)sb;                 // part[2][256]
    float ssq[4][4];
    #pragma unroll
    for (int mi = 0; mi < 4; ++mi)
        #pragma unroll
        for (int r = 0; r < 4; ++r) {
            float sq = 0.f;
            #pragma unroll
            for (int ni = 0; ni < 4; ++ni) { const float v = acc[mi][ni][r]; sq += v * v; }
            sq += __shfl_xor(sq, 1, 64);
            sq += __shfl_xor(sq, 2, 64);
            sq += __shfl_xor(sq, 4, 64);
            sq += __shfl_xor(sq, 8, 64);
            ssq[mi][r] = sq;
        }
    if (lm == 0) {
        #pragma unroll
        for (int mi = 0; mi < 4; ++mi)
            #pragma unroll
            for (int r = 0; r < 4; ++r)
                part[(w & 1) * 256 + wm + kq * 4 + mi * 16 + r] = ssq[mi][r];
    }
    __syncthreads();

    #pragma unroll
    for (int mi = 0; mi < 4; ++mi) {
        #pragma unroll
        for (int r = 0; r < 4; ++r) {
            const int rl = wm + kq * 4 + mi * 16 + r;
            const float inv = rsqrtf(part[rl] + part[256 + rl]);
            const long rg = m0 + rl;
            if (d.normMode == 1) {
                #pragma unroll
                for (int ni = 0; ni < 4; ++ni) {
                    const int col = n0 + wn + ni * 16 + lm;
                    ((_Float16*)d.C)[(long)g * 524288 + rg * 1024 + col] =
                        (_Float16)(acc[mi][ni][r] * inv);
                }
            } else if (n0 < 1024) {           // K half -> kn
                #pragma unroll
                for (int ni = 0; ni < 4; ++ni) {
                    const int col = n0 + wn + ni * 16 + lm;
                    ((_Float16*)d.C)[(long)g * 2097152 + rg * 1024 + col] =
                        (_Float16)(acc[mi][ni][r] * inv);
                }
            } else {                          // V half -> vn + x_ori
                #pragma unroll
                for (int ni = 0; ni < 4; ++ni) {
                    const int nL = n0 - 1024 + wn + ni * 16 + lm;
                    d.vnp[(long)g * 2097152 + rg * 1024 + nL] =
                        (_Float16)(acc[mi][ni][r] * inv);
                    if (rg < 512)
                        d.xop[(long)g * 524288 + rg * 1024 + nL] = (_Float16)acc[mi][ni][r];
                }
            }
        }
    }
    // vT raw transposed store (V half)
    if (d.normMode == 2 && n0 >= 1024) {
        #pragma unroll
        for (int mi = 0; mi < 4; ++mi)
            #pragma unroll
            for (int ni = 0; ni < 4; ++ni) {
                const int nL = n0 - 1024 + wn + ni * 16 + lm;
                half4v t;
                t.x = (_Float16)acc[mi][ni][0]; t.y = (_Float16)acc[mi][ni][1];
                t.z = (_Float16)acc[mi][ni][2]; t.w = (_Float16)acc[mi][ni][3];
                *(half4v*)(d.vtp + (long)g * 2097152 + (long)nL * 2048
                           + m0 + wm + kq * 4 + mi * 16) = t;
            }
    }
}

static GD mkgd(const _Float16* A, const _Float16* B, void* C, const float* cscale,
               long sAh, long sAg, long sBh, long sBg, long sSplit, long sCh, long sCg,
               int lda, int ldb, int ldc, int K, int SK, int hmask, int hshift,
               int ahx, int outHalf, int csMode, int nx, int ny, float alpha)
{
    GD d; d.A=A; d.B=B; d.C=C; d.colScale=cscale;
    d.vnp=nullptr; d.vtp=nullptr; d.xop=nullptr;
    d.sAh=sAh; d.sAg=sAg; d.sBh=sBh; d.sBg=sBg; d.sSplit=sSplit; d.sCh=sCh; d.sCg=sCg;
    d.lda=lda; d.ldb=ldb; d.ldc=ldc; d.K=K; d.SK=SK; d.hmask=hmask; d.hshift=hshift;
    d.ahx=ahx; d.outHalf=outHalf; d.csMode=csMode; d.nx=nx; d.ny=ny; d.normMode=0;
    d.alpha=alpha;
    return d;
}

// ---------------------------------------------------------------------------
// prep_all: grid (64,64,7). z<6: weight transposes (f32 -> f16 T);
// z==6: fp32->fp16 cast of x_cls|x_reg (lin = by*64+bx picks slice).
// ---------------------------------------------------------------------------
__global__ __launch_bounds__(256)
void prep_all(const float* __restrict__ x_cls, const float* __restrict__ x_reg,
              const float* __restrict__ Wq_c, const float* __restrict__ Wq_r,
              const float* __restrict__ Wkv_c, const float* __restrict__ Wkv_r,
              const float* __restrict__ Wl_c, const float* __restrict__ Wl_r,
              _Float16* __restrict__ xbf,
              _Float16* __restrict__ WqT, _Float16* __restrict__ WkvT,
              _Float16* __restrict__ WlinT)
{
    const int z = blockIdx.z;
    if (z == 6) {
        const int lin = blockIdx.y * 64 + blockIdx.x;    // [0,4096)
        const int which = lin >> 11;
        const int i = (lin & 2047) * 256 + threadIdx.x;  // float4 index
        const float* s = which ? x_reg : x_cls;
        const float4 v = ((const float4*)s)[i];
        half4v o;
        o.x = (_Float16)v.x; o.y = (_Float16)v.y; o.z = (_Float16)v.z; o.w = (_Float16)v.w;
        ((half4v*)(xbf + (size_t)which * 2097152))[i] = o;
        return;
    }
    __shared__ float t[32][33];
    const float* src; _Float16* dst; int ldsrc, lddst, nx, ky;
    switch (z) {
        case 0: src=Wq_c;  dst=WqT;            ldsrc=1024; lddst=1024; nx=32; ky=32; break;
        case 1: src=Wq_r;  dst=WqT+1048576;    ldsrc=1024; lddst=1024; nx=32; ky=32; break;
        case 2: src=Wkv_c; dst=WkvT;           ldsrc=2048; lddst=1024; nx=64; ky=32; break;
        case 3: src=Wkv_r; dst=WkvT+2097152;   ldsrc=2048; lddst=1024; nx=64; ky=32; break;
        case 4: src=Wl_c;  dst=WlinT;          ldsrc=2048; lddst=2048; nx=64; ky=64; break;
        default:src=Wl_r;  dst=WlinT+4194304;  ldsrc=2048; lddst=2048; nx=64; ky=64; break;
    }
    if ((int)blockIdx.x >= nx || (int)blockIdx.y >= ky) return;
    const int n0 = blockIdx.x << 5, k0 = blockIdx.y << 5;
    const int tx = threadIdx.x & 31, ty = threadIdx.x >> 5;
    #pragma unroll
    for (int j = ty; j < 32; j += 8)
        t[j][tx] = src[(size_t)(k0 + j) * ldsrc + n0 + tx];
    __syncthreads();
    #pragma unroll
    for (int j = ty; j < 32; j += 8)
        dst[(size_t)(n0 + j) * lddst + k0 + tx] = (_Float16)t[tx][j];
}

// ---------------------------------------------------------------------------
// Block reduces (256 threads, 4 waves). OP: 0 sum, 1 max.
// bred  : single value.  bred2: two values in ONE LDS round (half the barriers)
// ---------------------------------------------------------------------------
template<int OP>
__device__ __forceinline__ float bred(float v, float* lds)
{
    #pragma unroll
    for (int o = 32; o > 0; o >>= 1) {
        const float u = __shfl_xor(v, o, 64);
        v = OP ? fmaxf(v, u) : v + u;
    }
    __syncthreads();
    if ((threadIdx.x & 63) == 0) lds[threadIdx.x >> 6] = v;
    __syncthreads();
    return OP ? fmaxf(fmaxf(lds[0], lds[1]), fmaxf(lds[2], lds[3]))
              : lds[0] + lds[1] + lds[2] + lds[3];
}

template<int OP>
__device__ __forceinline__ void bred2(float& a, float& b, float* lds)
{
    #pragma unroll
    for (int o = 32; o > 0; o >>= 1) {
        const float ua = __shfl_xor(a, o, 64);
        const float ub = __shfl_xor(b, o, 64);
        a = OP ? fmaxf(a, ua) : a + ua;
        b = OP ? fmaxf(b, ub) : b + ub;
    }
    __syncthreads();
    if ((threadIdx.x & 63) == 0) {
        const int wi = threadIdx.x >> 6;
        lds[wi] = a; lds[4 + wi] = b;
    }
    __syncthreads();
    a = OP ? fmaxf(fmaxf(lds[0], lds[1]), fmaxf(lds[2], lds[3]))
           : lds[0] + lds[1] + lds[2] + lds[3];
    b = OP ? fmaxf(fmaxf(lds[4], lds[5]), fmaxf(lds[6], lds[7]))
           : lds[4] + lds[5] + lds[6] + lds[7];
}

// ---------------------------------------------------------------------------
// sb2 (vectorized, G13): thread t owns 8 CONTIGUOUS cols [t*8, t*8+8).
// half8 loads of S16, float4 loads of simPart, half8 stores of attn/wc/wr.
// Paired reductions via bred2 (one LDS round for cls+reg).
// S16 [16][512][2048] fp16 (0-7 cls, 8-15 reg); simPart [2][512][2048] f32.
// ---------------------------------------------------------------------------
__global__ __launch_bounds__(256)
void sb2_kernel(const _Float16* __restrict__ S16, const float* __restrict__ simPart,
                _Float16* __restrict__ attn,
                _Float16* __restrict__ wc, _Float16* __restrict__ wr)
{
    __shared__ float lds[8];
    const int q = blockIdx.x, t = threadIdx.x;
    const int c0 = t * 8;
    float asum[8] = {};
    for (int hh = 0; hh < 8; ++hh) {
        const size_t rb = (size_t)(hh * 512 + q) * 2048 + c0;
        const half8 hc = *(const half8*)(S16 + rb);
        const half8 hr = *(const half8*)(S16 + 8388608 + rb);
        float vc[8], vr[8];
        float mc = -1e30f, mr = -1e30f;
        #pragma unroll
        for (int j = 0; j < 8; ++j) {
            vc[j] = (float)hc[j]; vr[j] = (float)hr[j];
            mc = fmaxf(mc, vc[j]); mr = fmaxf(mr, vr[j]);
        }
        bred2<1>(mc, mr, lds);
        float sc = 0.f, sr = 0.f;
        #pragma unroll
        for (int j = 0; j < 8; ++j) {
            vc[j] = expf(vc[j] - mc); sc += vc[j];
            vr[j] = expf(vr[j] - mr); sr += vr[j];
        }
        bred2<0>(sc, sr, lds);
        const float ic = 0.5f / sc, ir = 0.5f / sr;
        half8 oa;
        #pragma unroll
        for (int j = 0; j < 8; ++j) {
            const float a = vc[j] * ic + vr[j] * ir;
            oa[j] = (_Float16)a;
            asum[j] += a;
        }
        *(half8*)(attn + rb) = oa;
    }
    float mx = -1e30f;
    #pragma unroll
    for (int j = 0; j < 8; ++j) { asum[j] *= 0.125f; mx = fmaxf(mx, asum[j]); }
    mx = bred<1>(mx, lds);
    const size_t qb = (size_t)q * 2048 + c0;
    const float4 sa = *(const float4*)(simPart + qb);
    const float4 sb_ = *(const float4*)(simPart + qb + 4);
    const float4 ra = *(const float4*)(simPart + 1048576 + qb);
    const float4 rb_ = *(const float4*)(simPart + 1048576 + qb + 4);
    const float sim[8] = {sa.x, sa.y, sa.z, sa.w, sb_.x, sb_.y, sb_.z, sb_.w};
    const float reg[8] = {ra.x, ra.y, ra.z, ra.w, rb_.x, rb_.y, rb_.z, rb_.w};
    float em[8], emo[8];
    float s1 = 0.f, s2 = 0.f;
    #pragma unroll
    for (int j = 0; j < 8; ++j) {
        const float e = expf(asum[j] - mx);
        const float m  = sim[j] > 0.75f ? 1.f : 0.f;
        const float mo = reg[j] > 0.99f ? 1.f : 0.f;
        em[j] = e * m; emo[j] = e * m * mo;
        s1 += em[j]; s2 += emo[j];
    }
    bred2<0>(s1, s2, lds);
    const float i1 = 1.f / s1, i2 = 1.f / s2;
    half8 o1, o2;
    #pragma unroll
    for (int j = 0; j < 8; ++j) {
        o1[j] = (_Float16)(em[j] * i1);
        o2[j] = (_Float16)(emo[j] * i2);
    }
    *(half8*)(wc + qb) = o1;
    *(half8*)(wr + qb) = o2;
}

// ---------------------------------------------------------------------------
// xcat16 [2][512][2048] (vectorized half8): cols<1024 = 4-way reduce of fp16
// attn@V partials, cols>=1024 = x_ori copy. Grid 1024 x 256.
// ---------------------------------------------------------------------------
__global__ __launch_bounds__(256)
void build_xcat(const _Float16* __restrict__ xcatPart, const _Float16* __restrict__ x_ori,
                _Float16* __restrict__ xcat)
{
    const int v8 = blockIdx.x * 256 + threadIdx.x;    // [0, 262144)
    const size_t base = (size_t)v8 * 8;
    const int j = (int)(base & 2047);
    const int n = (int)((base >> 11) & 511);
    const int g = (int)(base >> 20);
    half8 o;
    if (j < 1024) {
        const size_t p = (size_t)g * 524288 + (size_t)n * 1024 + j;
        float a[8] = {};
        #pragma unroll
        for (int s = 0; s < 4; ++s) {
            const half8 v = *(const half8*)(xcatPart + (size_t)s * 1048576 + p);
            #pragma unroll
            for (int k = 0; k < 8; ++k) a[k] += (float)v[k];
        }
        #pragma unroll
        for (int k = 0; k < 8; ++k) o[k] = (_Float16)a[k];
    } else {
        o = *(const half8*)(x_ori + (size_t)g * 524288 + (size_t)n * 1024 + (j - 1024));
    }
    *(half8*)(xcat + base) = o;
}

// ---------------------------------------------------------------------------
// finalize d_out [2][512][3072] (vectorized float4): cols<1024 4-way avePart
// reduce; cols>=1024 4-way outPart reduce + bias. Grid 3072 x 256.
// ---------------------------------------------------------------------------
__global__ __launch_bounds__(256)
void finalize(const float* __restrict__ avePart, const float* __restrict__ outPart,
              const float* __restrict__ b_lin, const float* __restrict__ b_lin_reg,
              float* __restrict__ out)
{
    const int v4 = blockIdx.x * 256 + threadIdx.x;    // [0, 786432)
    const size_t base = (size_t)v4 * 4;
    const int c = (int)(base % 3072);
    const int r = (int)((base / 3072) & 511);
    const int g = (int)(base / (3072 * 512));
    float4 v;
    if (c < 1024) {
        const size_t p = (size_t)g * 524288 + (size_t)r * 1024 + c;
        v = make_float4(0.f, 0.f, 0.f, 0.f);
        #pragma unroll
        for (int s = 0; s < 4; ++s) {
            const float4 u = *(const float4*)(avePart + (size_t)s * 1048576 + p);
            v.x += u.x; v.y += u.y; v.z += u.z; v.w += u.w;
        }
    } else {
        const int cc = c - 1024;
        v = *(const float4*)((g ? b_lin_reg : b_lin) + cc);
        const size_t p = (size_t)g * 1048576 + (size_t)r * 2048 + cc;
        #pragma unroll
        for (int s = 0; s < 4; ++s) {
            const float4 u = *(const float4*)(outPart + (size_t)s * 2097152 + p);
            v.x += u.x; v.y += u.y; v.z += u.z; v.w += u.w;
        }
    }
    *(float4*)(out + base) = v;
}

extern "C" void kernel_launch(void* const* d_in, const int* in_sizes, int n_in,
                              void* d_out, int out_size, void* d_ws, size_t ws_size,
                              hipStream_t stream)
{
    const float* x_cls     = (const float*)d_in[0];
    const float* x_reg     = (const float*)d_in[1];
    const float* cls_score = (const float*)d_in[2];
    const float* W_q_cls   = (const float*)d_in[4];
    const float* W_kv_cls  = (const float*)d_in[5];
    const float* W_q_reg   = (const float*)d_in[6];
    const float* W_kv_reg  = (const float*)d_in[7];
    const float* W_lin     = (const float*)d_in[8];
    const float* b_lin     = (const float*)d_in[9];
    const float* W_lin_reg = (const float*)d_in[10];
    const float* b_lin_reg = (const float*)d_in[11];
    float* out = (float*)d_out;

    if (ws_size < (size_t)124 * 1048576) return;

    // Workspace overlay (MiB offsets):
    char* W = (char*)d_ws;
    auto at = [&](size_t mb) { return (void*)(W + mb * 1048576); };
    _Float16* WlinT   = (_Float16*)at(0);    // prep -> M8                 [0,16)
    _Float16* vT      = (_Float16*)at(16);   // M1 -> M3                   [16,24)
    _Float16* x_ori   = (_Float16*)at(24);   // M1 -> build_xcat           [24,26)
    _Float16* w_c     = (_Float16*)at(26);   // sb2 -> M3                  [26,28)
    _Float16* w_r     = (_Float16*)at(28);   //                            [28,30)
    _Float16* qn      = (_Float16*)at(30);   // M1 -> M2                   [30,32)
    float*    simPart = (float*)at(32);      // M2 -> sb2                  [32,40)
    float*    outPart = (float*)at(32);      // M8 -> finalize (sim dead)  [32,64)
    _Float16* kn      = (_Float16*)at(40);   // M1 -> M2                   [40,48)
    _Float16* vn      = (_Float16*)at(48);   // M1 -> M2                   [48,56)
    _Float16* attn_h  = (_Float16*)at(40);   // sb2 -> M3 (kn/vn dead)     [40,56)
    _Float16* xbf     = (_Float16*)at(56);   // prep -> M1                 [56,64)
    _Float16* WqT     = (_Float16*)at(64);   // prep -> M1                 [64,68)
    _Float16* xcat16  = (_Float16*)at(64);   // build_xcat -> M8 (WqT dead)[64,68)
    _Float16* WkvT    = (_Float16*)at(68);   // prep -> M1                 [68,76)
    _Float16* S16     = (_Float16*)at(76);   // M2 -> sb2                  [76,108)
    _Float16* xcatPart= (_Float16*)at(76);   // M3 -> build_xcat (S16 dead)[76,84)
    float*    avePart = (float*)at(84);      // M3 -> finalize             [84,100)

    // Phase 1: prep (cast + all transposes, one launch)
    prep_all<<<dim3(64, 64, 7), 256, 0, stream>>>(
        x_cls, x_reg, W_q_cls, W_q_reg, W_kv_cls, W_kv_reg, W_lin, W_lin_reg,
        xbf, WqT, WkvT, WlinT);

    // Phase 2 (M1): q-proj + kv-proj with fused L2-norm epilogues
    {
        GD q  = mkgd(xbf, WqT, qn, nullptr,
                     0, 2097152, 0, 1048576, 0, 0, 0,
                     1024, 1024, 1024, 1024, 1, 0, 0, 1, 0, 0, 8, 2, 1.f);
        q.normMode = 1;
        GD kv = mkgd(xbf, WkvT, kn, nullptr,
                     0, 2097152, 0, 2097152, 0, 0, 0,
                     1024, 1024, 1024, 1024, 1, 0, 0, 1, 0, 0, 16, 8, 1.f);
        kv.normMode = 2; kv.vnp = vn; kv.vtp = vT; kv.xop = x_ori;
        hgemm3<<<dim3(16, 8, 4), 512, 0, stream>>>(q, kv, 2);
    }

    // Phase 4 (M2): v-sim (fp32 direct) + scores (z=16, fp16)
    {
        GD vs = mkgd(vn, vn, simPart, nullptr,
                     0, 2097152, 0, 2097152, 0, 0, 1048576,
                     1024, 1024, 2048, 1024, 1, 0, 0, 0, 0, 0, 16, 2, 0.125f);
        GD sc = mkgd(qn, kn, S16, cls_score,
                     128, 524288, 128, 2097152, 0, 1048576, 8388608,
                     1024, 1024, 2048, 128, 1, 7, 3, 0, 1, 2, 16, 2, 25.f);
        hgemm3<<<dim3(16, 2, 18), 512, 0, stream>>>(vs, sc, 2);
    }

    // Phase 5: fused dual softmax + blend + head-mean + round2 weights
    sb2_kernel<<<512, 256, 0, stream>>>(S16, simPart, attn_h, w_c, w_r);

    // Phase 6 (M3): attn@V (AHX, SK=4, fp16 partials) + ave (SK=4, f32)
    {
        GD av = mkgd(attn_h, vT, xcatPart, nullptr,
                     1048576, 0, 0, 2097152, 1048576, 0, 524288,
                     2048, 2048, 1024, 2048, 4, 0, 0, 1, 1, 0, 8, 2, 1.f);
        GD ae = mkgd(w_c, vT, avePart, nullptr,
                     0, 1048576, 0, 2097152, 1048576, 0, 524288,
                     2048, 2048, 1024, 2048, 4, 0, 0, 0, 0, 0, 8, 2, 1.f);
        hgemm3<<<dim3(8, 2, 16), 512, 0, stream>>>(av, ae, 8);
    }

    // Phase 7: xcat assembly (4-way fp16 reduce + x_ori), half8-vectorized
    build_xcat<<<1024, 256, 0, stream>>>(xcatPart, x_ori, xcat16);

    // Phase 8 (M8): out-linears (SK=4, fp32 partials)
    {
        GD ol = mkgd(xcat16, WlinT, outPart, nullptr,
                     0, 1048576, 0, 4194304, 2097152, 0, 1048576,
                     2048, 2048, 2048, 2048, 4, 0, 0, 0, 0, 0, 16, 2, 1.f);
        hgemm3<<<dim3(16, 2, 8), 512, 0, stream>>>(ol, ol, 8);
    }

    // Phase 9: write d_out, float4-vectorized
    finalize<<<3072, 256, 0, stream>>>(avePart, outPart, b_lin, b_lin_reg, out);
}